// Round 6
// baseline (854.847 us; speedup 1.0000x reference)
//
#include <hip/hip_runtime.h>
#include <math.h>

#define S 4096
#define H 1024
#define FF 3072
#define G 100
#define MAXSPAN 30
#define MAXK 819
#define NBAND (S * MAXSPAN)   // 122880 slots, 122445 valid
#define BAND_COUNT 122445.0

// out layout (float32)
#define O_START 0
#define O_END   819
#define O_MASK  1638
#define O_SEQ   2457
#define O_COST  (2457 + S * H)   // 4196761

typedef __bf16 bf16x8 __attribute__((ext_vector_type(8)));
typedef float f32x16 __attribute__((ext_vector_type(16)));

// ---------------- helpers ----------------

__device__ __forceinline__ float block_reduce_256(float x, volatile float* red) {
  #pragma unroll
  for (int off = 32; off > 0; off >>= 1) x += __shfl_down(x, off, 64);
  int wid = threadIdx.x >> 6;
  int lane = threadIdx.x & 63;
  __syncthreads();
  if (lane == 0) red[wid] = x;
  __syncthreads();
  return red[0] + red[1] + red[2] + red[3];
}

__device__ __forceinline__ float block_reduce_1024(float x, volatile float* red) {
  #pragma unroll
  for (int off = 32; off > 0; off >>= 1) x += __shfl_down(x, off, 64);
  int wid = threadIdx.x >> 6;   // 0..15
  int lane = threadIdx.x & 63;
  __syncthreads();
  if (lane == 0) red[wid] = x;
  __syncthreads();
  float s = 0.f;
  #pragma unroll
  for (int q = 0; q < 16; q++) s += red[q];
  return s;
}

__device__ __forceinline__ unsigned f2key(float f) {
  unsigned b = __float_as_uint(f);
  return (b & 0x80000000u) ? ~b : (b | 0x80000000u);
}

__device__ __forceinline__ unsigned short bf16_rne(float x) {
  unsigned u = __float_as_uint(x);
  unsigned r = ((u >> 16) & 1u) + 0x7FFFu;
  return (unsigned short)((u + r) >> 16);
}

__device__ __forceinline__ void split2(float x, unsigned short& h, unsigned short& l) {
  h = bf16_rne(x);
  float hf = __uint_as_float(((unsigned)h) << 16);
  l = bf16_rne(x - hf);
}

__device__ __forceinline__ void gld16(const void* g, void* l) {
  __builtin_amdgcn_global_load_lds(
      (const __attribute__((address_space(1))) unsigned int*)g,
      (__attribute__((address_space(3))) unsigned int*)l, 16, 0, 0);
}

// ---------------- prep: gw vectors + zero accumulators ----------------

__global__ __launch_bounds__(256) void prep_kernel(const float* __restrict__ g_sm,
                                                   const float* __restrict__ w_st,
                                                   const float* __restrict__ g_em,
                                                   const float* __restrict__ w_en,
                                                   float* __restrict__ gwS,
                                                   float* __restrict__ gwE,
                                                   float* __restrict__ sums,   // 6*S
                                                   double* __restrict__ jacc) {
  int i = blockIdx.x * 256 + threadIdx.x;
  if (i < FF) gwS[i] = g_sm[i] * w_st[i];
  else if (i < 2 * FF) gwE[i - FF] = g_em[i - FF] * w_en[i - FF];
  if (i < 6 * S) sums[i] = 0.0f;
  if (i == 0) *jacc = 0.0;
}

// ---------------- pack kernels: f32 -> hi/lo bf16, tiled [panel][kq][r][8] ----------------
// tiled element offset = panel*(128*K) + kq*1024 + r*8 + s   (panel = row/128, kq = k/8)

__global__ __launch_bounds__(256) void pack_a_kernel(const float* __restrict__ A,
                                                     unsigned short* __restrict__ hi,
                                                     unsigned short* __restrict__ lo,
                                                     int K) {
  __shared__ float tile[32][33];
  const int t = threadIdx.x;
  const int tx = t & 31, ty8 = t >> 5;
  const int k0 = blockIdx.x * 32, r0 = blockIdx.y * 32;
  #pragma unroll
  for (int r = ty8; r < 32; r += 8)
    tile[r][tx] = A[(size_t)(r0 + r) * K + k0 + tx];
  __syncthreads();
  if (t < 128) {
    const int kql = t >> 5;
    const int rl = t & 31;
    unsigned short h8[8], l8[8];
    #pragma unroll
    for (int s = 0; s < 8; s++) split2(tile[rl][kql * 8 + s], h8[s], l8[s]);
    const size_t panel = (size_t)(r0 >> 7);
    const int rloc = (r0 & 127) + rl;
    const size_t off = panel * (size_t)(128 * K) + (size_t)(k0 / 8 + kql) * 1024 + (size_t)rloc * 8;
    *(uint4*)(hi + off) = *(const uint4*)h8;
    *(uint4*)(lo + off) = *(const uint4*)l8;
  }
}

// A-side with fused LayerNorm: val = (A - mu[row]) * rstd[row] * g[k] + beta[k]
__global__ __launch_bounds__(256) void pack_ln_a_kernel(const float* __restrict__ A,
                                                        const float* __restrict__ mu,
                                                        const float* __restrict__ rstd,
                                                        const float* __restrict__ g,
                                                        const float* __restrict__ beta,
                                                        unsigned short* __restrict__ hi,
                                                        unsigned short* __restrict__ lo,
                                                        int K) {
  __shared__ float tile[32][33];
  const int t = threadIdx.x;
  const int tx = t & 31, ty8 = t >> 5;
  const int k0 = blockIdx.x * 32, r0 = blockIdx.y * 32;
  #pragma unroll
  for (int r = ty8; r < 32; r += 8)
    tile[r][tx] = A[(size_t)(r0 + r) * K + k0 + tx];
  __syncthreads();
  if (t < 128) {
    const int kql = t >> 5;
    const int rl = t & 31;
    const int row = r0 + rl;
    const float m = mu[row], rs = rstd[row];
    float4 g0 = *(const float4*)(g + k0 + kql * 8);
    float4 g1 = *(const float4*)(g + k0 + kql * 8 + 4);
    float4 b0 = *(const float4*)(beta + k0 + kql * 8);
    float4 b1 = *(const float4*)(beta + k0 + kql * 8 + 4);
    float gv[8] = {g0.x, g0.y, g0.z, g0.w, g1.x, g1.y, g1.z, g1.w};
    float bv[8] = {b0.x, b0.y, b0.z, b0.w, b1.x, b1.y, b1.z, b1.w};
    unsigned short h8[8], l8[8];
    #pragma unroll
    for (int s = 0; s < 8; s++) {
      float v = (tile[rl][kql * 8 + s] - m) * rs * gv[s] + bv[s];
      split2(v, h8[s], l8[s]);
    }
    const size_t panel = (size_t)(r0 >> 7);
    const int rloc = (r0 & 127) + rl;
    const size_t off = panel * (size_t)(128 * K) + (size_t)(k0 / 8 + kql) * 1024 + (size_t)rloc * 8;
    *(uint4*)(hi + off) = *(const uint4*)h8;
    *(uint4*)(lo + off) = *(const uint4*)l8;
  }
}

__device__ __forceinline__ void pack_bt_body(const float* __restrict__ W,
                                             unsigned short* __restrict__ hi,
                                             unsigned short* __restrict__ lo,
                                             int K, int N) {
  __shared__ float tile[32][33];   // tile[k_local][n_local]
  const int t = threadIdx.x;
  const int tx = t & 31, ty8 = t >> 5;
  const int k0 = blockIdx.x * 32, n0 = blockIdx.y * 32;
  #pragma unroll
  for (int r = ty8; r < 32; r += 8)
    tile[r][tx] = W[(size_t)(k0 + r) * N + n0 + tx];
  __syncthreads();
  if (t < 128) {
    const int kql = t >> 5;
    const int nl = t & 31;
    unsigned short h8[8], l8[8];
    #pragma unroll
    for (int s = 0; s < 8; s++) split2(tile[kql * 8 + s][nl], h8[s], l8[s]);
    const size_t panel = (size_t)(n0 >> 7);
    const int nloc = (n0 & 127) + nl;
    const size_t off = panel * (size_t)(128 * K) + (size_t)(k0 / 8 + kql) * 1024 + (size_t)nloc * 8;
    *(uint4*)(hi + off) = *(const uint4*)h8;
    *(uint4*)(lo + off) = *(const uint4*)l8;
  }
}

__global__ __launch_bounds__(256) void pack_bt_kernel(const float* __restrict__ W,
                                                      unsigned short* __restrict__ hi,
                                                      unsigned short* __restrict__ lo,
                                                      int K, int N) {
  pack_bt_body(W, hi, lo, K, N);
}

// both H x FF weights in one dispatch
__global__ __launch_bounds__(256) void pack_bt_dual_kernel(const float* __restrict__ W1,
                                                           const float* __restrict__ W2,
                                                           unsigned short* __restrict__ h1,
                                                           unsigned short* __restrict__ l1,
                                                           unsigned short* __restrict__ h2,
                                                           unsigned short* __restrict__ l2,
                                                           int K, int N) {
  if (blockIdx.z == 0) pack_bt_body(W1, h1, l1, K, N);
  else                 pack_bt_body(W2, h2, l2, K, N);
}

// ---------------- MFMA GEMM core (32x32x16, 3-product split) ----------------
// EPI 0: bias only. EPI 1: gelu(bias+) + per-row stats atomics (sumH, sumH2, sumHW).

template <int EPI>
__device__ __forceinline__ void gemm_body(const char* cAh, const char* cAl,
                                          const char* cBh, const char* cBl,
                                          const float* __restrict__ bias,
                                          float* __restrict__ C,
                                          const float* __restrict__ gw,
                                          float* __restrict__ sums,   // [3*S]: H, H2, HW
                                          int bm, int bn, int N, int K,
                                          char* smem) {
  const int tid = threadIdx.x;
  const int lane = tid & 63;
  const int wid = __builtin_amdgcn_readfirstlane(tid >> 6);
  const int wm = wid >> 1, wn = wid & 1;
  const int lb = lane * 16;
  const int ldsq = wid * 2048;

  const int khalf = lane >> 5;
  const int r31 = lane & 31;
  const int abase = khalf * 2048 + (wm * 64 + r31) * 16;
  const int bbase = khalf * 2048 + (wn * 64 + r31) * 16;

  f32x16 acc[2][2];
  #pragma unroll
  for (int a = 0; a < 2; a++)
    #pragma unroll
    for (int b = 0; b < 2; b++)
      #pragma unroll
      for (int r = 0; r < 16; r++) acc[a][b][r] = 0.0f;

  for (int k0 = 0; k0 < K; k0 += 32) {
    const size_t qb = (size_t)((k0 >> 3) + wid) * 2048 + lb;
    __syncthreads();
    gld16(cAh + qb,        smem +     0 + ldsq);
    gld16(cAh + qb + 1024, smem +     0 + ldsq + 1024);
    gld16(cAl + qb,        smem +  8192 + ldsq);
    gld16(cAl + qb + 1024, smem +  8192 + ldsq + 1024);
    gld16(cBh + qb,        smem + 16384 + ldsq);
    gld16(cBh + qb + 1024, smem + 16384 + ldsq + 1024);
    gld16(cBl + qb,        smem + 24576 + ldsq);
    gld16(cBl + qb + 1024, smem + 24576 + ldsq + 1024);
    __syncthreads();

    bf16x8 ah[2][2], al[2][2], bh[2][2], bl[2][2];
    #pragma unroll
    for (int ks = 0; ks < 2; ks++) {
      #pragma unroll
      for (int mt = 0; mt < 2; mt++) {
        ah[ks][mt] = *(const bf16x8*)(smem +     0 + ks * 4096 + abase + mt * 512);
        al[ks][mt] = *(const bf16x8*)(smem +  8192 + ks * 4096 + abase + mt * 512);
      }
      #pragma unroll
      for (int nt = 0; nt < 2; nt++) {
        bh[ks][nt] = *(const bf16x8*)(smem + 16384 + ks * 4096 + bbase + nt * 512);
        bl[ks][nt] = *(const bf16x8*)(smem + 24576 + ks * 4096 + bbase + nt * 512);
      }
    }
    #pragma unroll
    for (int ks = 0; ks < 2; ks++)
      #pragma unroll
      for (int mt = 0; mt < 2; mt++)
        #pragma unroll
        for (int nt = 0; nt < 2; nt++) {
          acc[mt][nt] = __builtin_amdgcn_mfma_f32_32x32x16_bf16(ah[ks][mt], bh[ks][nt], acc[mt][nt], 0, 0, 0);
          acc[mt][nt] = __builtin_amdgcn_mfma_f32_32x32x16_bf16(al[ks][mt], bh[ks][nt], acc[mt][nt], 0, 0, 0);
          acc[mt][nt] = __builtin_amdgcn_mfma_f32_32x32x16_bf16(ah[ks][mt], bl[ks][nt], acc[mt][nt], 0, 0, 0);
        }
  }

  // epilogue: col=lane&31, row=(reg&3)+8*(reg>>2)+4*khalf
  float gwc[2];
  if (EPI == 1) {
    gwc[0] = gw[bn + wn * 64 + r31];
    gwc[1] = gw[bn + wn * 64 + 32 + r31];
  }
  #pragma unroll
  for (int mt = 0; mt < 2; mt++) {
    #pragma unroll
    for (int nt = 0; nt < 2; nt++) {
      const int colg = bn + wn * 64 + nt * 32 + r31;
      const float bb = bias[colg];
      #pragma unroll
      for (int reg = 0; reg < 16; reg++) {
        const int rowl = (reg & 3) + 8 * (reg >> 2) + 4 * khalf;
        const int rowg = bm + wm * 64 + mt * 32 + rowl;
        float v = acc[mt][nt][reg] + bb;
        if (EPI == 1) {
          v = 0.5f * v * (1.0f + erff(v * 0.70710678118654752f));
          acc[mt][nt][reg] = v;   // keep for stats
        }
        C[(size_t)rowg * N + colg] = v;
      }
    }
  }
  if (EPI == 1) {
    #pragma unroll
    for (int mt = 0; mt < 2; mt++) {
      #pragma unroll
      for (int reg = 0; reg < 16; reg++) {
        float v0 = acc[mt][0][reg], v1 = acc[mt][1][reg];
        float h = v0 + v1;
        float h2 = v0 * v0 + v1 * v1;
        float hw = v0 * gwc[0] + v1 * gwc[1];
        #pragma unroll
        for (int off = 16; off > 0; off >>= 1) {
          h  += __shfl_down(h,  off, 32);
          h2 += __shfl_down(h2, off, 32);
          hw += __shfl_down(hw, off, 32);
        }
        if (r31 == 0) {
          const int rowg = bm + wm * 64 + mt * 32 + (reg & 3) + 8 * (reg >> 2) + 4 * khalf;
          atomicAdd(&sums[rowg], h);
          atomicAdd(&sums[S + rowg], h2);
          atomicAdd(&sums[2 * S + rowg], hw);
        }
      }
    }
  }
}

// GEMM3: single output, no stats
__global__ __launch_bounds__(256) void gemm_mfma_kernel(const unsigned short* __restrict__ Ahi,
                                                        const unsigned short* __restrict__ Alo,
                                                        const unsigned short* __restrict__ Bhi,
                                                        const unsigned short* __restrict__ Blo,
                                                        const float* __restrict__ bias,
                                                        float* __restrict__ C,
                                                        int N, int K) {
  __shared__ __align__(16) char smem[32768];
  const size_t panAb = (size_t)blockIdx.y * (size_t)(128 * K) * 2;
  const size_t panBb = (size_t)blockIdx.x * (size_t)(128 * K) * 2;
  gemm_body<0>((const char*)Ahi + panAb, (const char*)Alo + panAb,
               (const char*)Bhi + panBb, (const char*)Blo + panBb,
               bias, C, nullptr, nullptr,
               blockIdx.y * 128, blockIdx.x * 128, N, K, smem);
}

// GEMM1+2 fused: blockIdx.z picks branch; gelu + row-stats epilogue
__global__ __launch_bounds__(256) void gemm_mfma_dual_kernel(const unsigned short* __restrict__ Ahi,
                                                             const unsigned short* __restrict__ Alo,
                                                             const unsigned short* __restrict__ B1hi,
                                                             const unsigned short* __restrict__ B1lo,
                                                             const unsigned short* __restrict__ B2hi,
                                                             const unsigned short* __restrict__ B2lo,
                                                             const float* __restrict__ bias1,
                                                             const float* __restrict__ bias2,
                                                             float* __restrict__ C1,
                                                             float* __restrict__ C2,
                                                             const float* __restrict__ gwS,
                                                             const float* __restrict__ gwE,
                                                             float* __restrict__ sums,  // 6*S
                                                             int N, int K) {
  __shared__ __align__(16) char smem[32768];
  const int zb = blockIdx.z;
  const unsigned short* Bhi = zb ? B2hi : B1hi;
  const unsigned short* Blo = zb ? B2lo : B1lo;
  const float* bias = zb ? bias2 : bias1;
  const float* gw = zb ? gwE : gwS;
  float* C = zb ? C2 : C1;
  float* sb = sums + (zb ? 3 * S : 0);
  const size_t panAb = (size_t)blockIdx.y * (size_t)(128 * K) * 2;
  const size_t panBb = (size_t)blockIdx.x * (size_t)(128 * K) * 2;
  gemm_body<1>((const char*)Ahi + panAb, (const char*)Alo + panAb,
               (const char*)Bhi + panBb, (const char*)Blo + panBb,
               bias, C, gw, sb,
               blockIdx.y * 128, blockIdx.x * 128, N, K, smem);
}

// ---------------- LN finalize from sums: mu, rstd, logit ----------------
// grid (S/256, 2); logit = rstd*(sumHW - mu*Σgw) + Σβ·w + b

__global__ __launch_bounds__(256) void ln_finalize_kernel(const float* __restrict__ sums,  // 6*S
                                                          const float* __restrict__ gwS,
                                                          const float* __restrict__ beS,
                                                          const float* __restrict__ wS,
                                                          const float* __restrict__ bS,
                                                          const float* __restrict__ gwE,
                                                          const float* __restrict__ beE,
                                                          const float* __restrict__ wE,
                                                          const float* __restrict__ bE,
                                                          float* __restrict__ muS,
                                                          float* __restrict__ rstdS,
                                                          float* __restrict__ slog,
                                                          float* __restrict__ muE,
                                                          float* __restrict__ rstdE,
                                                          float* __restrict__ elog) {
  __shared__ float red[4];
  const int br = blockIdx.y, tid = threadIdx.x;
  const float* gw = br ? gwE : gwS;
  const float* beta = br ? beE : beS;
  const float* w = br ? wE : wS;
  const float* bsc = br ? bE : bS;
  const float* sb = sums + (br ? 3 * S : 0);

  float a = 0.f, b = 0.f;
  for (int k = tid; k < FF; k += 256) { a += gw[k]; b += beta[k] * w[k]; }
  float sgw = block_reduce_256(a, red);
  float sbw = block_reduce_256(b, red);

  const int row = blockIdx.x * 256 + tid;
  float sh = sb[row], sh2 = sb[S + row], shw = sb[2 * S + row];
  float mu = sh * (1.0f / (float)FF);
  float var = fmaxf(sh2 * (1.0f / (float)FF) - mu * mu, 0.0f);
  float rstd = rsqrtf(var + 1e-5f);
  float lg = rstd * (shw - mu * sgw) + sbw + bsc[0];
  if (br) { muE[row] = mu; rstdE[row] = rstd; elog[row] = lg; }
  else    { muS[row] = mu; rstdS[row] = rstd; slog[row] = lg; }
}

// ---------------- band joint (tiled, LDS E-chunk, inline E-LayerNorm, fused junk sum) ----------------

__global__ __launch_bounds__(256) void band_joint_kernel(const float* __restrict__ T,
                                                         const float* __restrict__ Eraw,
                                                         const float* __restrict__ muE,
                                                         const float* __restrict__ rstdE,
                                                         const float* __restrict__ gE,
                                                         const float* __restrict__ betaE,
                                                         const float* __restrict__ sl,
                                                         const float* __restrict__ el,
                                                         float* __restrict__ band,
                                                         double* __restrict__ jacc) {
  __shared__ float Elds[45][260];   // 260 = 256 + 4 pad
  __shared__ float red[4];
  const int t = threadIdx.x;
  const int bx = blockIdx.x;
  const int sbx = (bx & 7) * 32 + (bx >> 3);   // XCD-locality swizzle (perf heuristic)
  const int i0 = sbx * 16;
  const int r_l = t >> 4, c = t & 15;

  float accd[MAXSPAN];
  #pragma unroll
  for (int d = 0; d < MAXSPAN; d++) accd[d] = 0.0f;

  for (int k0 = 0; k0 < FF; k0 += 256) {
    const float* trow = T + (size_t)(i0 + r_l) * FF + k0 + c * 16;
    float4 tv0 = *(const float4*)(trow + 0);
    float4 tv1 = *(const float4*)(trow + 4);
    float4 tv2 = *(const float4*)(trow + 8);
    float4 tv3 = *(const float4*)(trow + 12);
    __syncthreads();
    for (int rr = t >> 6; rr < 45; rr += 4) {
      int gr = i0 + rr;
      int cc = (t & 63) * 4;
      float4 rv = {0.f, 0.f, 0.f, 0.f};
      if (gr < S) {
        float4 ev = *(const float4*)(Eraw + (size_t)gr * FF + k0 + cc);
        float m = muE[gr], rs = rstdE[gr];
        float4 gv = *(const float4*)(gE + k0 + cc);
        float4 bv = *(const float4*)(betaE + k0 + cc);
        rv.x = (ev.x - m) * rs * gv.x + bv.x;
        rv.y = (ev.y - m) * rs * gv.y + bv.y;
        rv.z = (ev.z - m) * rs * gv.z + bv.z;
        rv.w = (ev.w - m) * rs * gv.w + bv.w;
      }
      *(float4*)&Elds[rr][cc] = rv;
    }
    __syncthreads();
    #pragma unroll
    for (int d = 0; d < MAXSPAN; d++) {
      const float* er = &Elds[r_l + d][c * 16];
      float4 e0 = *(const float4*)(er + 0);
      float4 e1 = *(const float4*)(er + 4);
      float4 e2 = *(const float4*)(er + 8);
      float4 e3 = *(const float4*)(er + 12);
      accd[d] += tv0.x * e0.x + tv0.y * e0.y + tv0.z * e0.z + tv0.w * e0.w
               + tv1.x * e1.x + tv1.y * e1.y + tv1.z * e1.z + tv1.w * e1.w
               + tv2.x * e2.x + tv2.y * e2.y + tv2.z * e2.z + tv2.w * e2.w
               + tv3.x * e3.x + tv3.y * e3.y + tv3.z * e3.z + tv3.w * e3.w;
    }
  }

  const int i = i0 + r_l;
  const float my_sl = sl[i];
  float jsum = 0.0f;
  #pragma unroll
  for (int d = 0; d < MAXSPAN; d++) {
    float v = accd[d];
    v += __shfl_down(v, 8, 16);
    v += __shfl_down(v, 4, 16);
    v += __shfl_down(v, 2, 16);
    v += __shfl_down(v, 1, 16);
    if (c == 0) {
      int j = i + d;
      if (j < S) {
        float vv = v + my_sl + el[j];
        vv = fminf(fmaxf(vv, -10000.0f), 10000.0f);
        band[i * MAXSPAN + d] = vv;
        float p = 1.0f / (1.0f + expf(-vv));
        jsum += fmaxf(logf(1.0f - p), -100.0f);
      } else {
        band[i * MAXSPAN + d] = -1e30f;
      }
    }
  }
  float tot = block_reduce_256(jsum, red);
  if (t == 0) atomicAdd(jacc, (double)tot);
}

// ---------------- top-k + cost finalize (single block) ----------------

__global__ __launch_bounds__(1024) void topk_finalize_kernel(const float* __restrict__ band,
                                                             const int* __restrict__ gold,
                                                             const double* __restrict__ jacc,
                                                             float* __restrict__ out) {
  __shared__ int hist[256];
  __shared__ unsigned sh_prefix;
  __shared__ int sh_remk;
  __shared__ int idxbuf[1024];
  __shared__ unsigned tkey[256];
  __shared__ int tidx[256];
  __shared__ int cnt_gt, cnt_eq;
  __shared__ int sb[1024];
  __shared__ int gcell[G];
  __shared__ float redf[16];
  const int tid = threadIdx.x;

  // pass 0: top 8 bits
  if (tid < 256) hist[tid] = 0;
  __syncthreads();
  for (int e = tid; e < NBAND; e += 1024)
    atomicAdd(&hist[f2key(band[e]) >> 24], 1);
  __syncthreads();
  if (tid == 0) {
    int cum = 0, b = 255;
    for (; b > 0; b--) {
      if (cum + hist[b] >= MAXK) break;
      cum += hist[b];
    }
    sh_prefix = (unsigned)b;
    sh_remk = MAXK - cum;
  }
  __syncthreads();
  const unsigned p8 = sh_prefix;
  int remk = sh_remk;
  __syncthreads();

  // pass 1: bits 23..16 within prefix
  if (tid < 256) hist[tid] = 0;
  __syncthreads();
  for (int e = tid; e < NBAND; e += 1024) {
    unsigned key = f2key(band[e]);
    if ((key >> 24) == p8) atomicAdd(&hist[(key >> 16) & 255], 1);
  }
  __syncthreads();
  if (tid == 0) {
    int cum = 0, b = 255;
    for (; b > 0; b--) {
      if (cum + hist[b] >= remk) break;
      cum += hist[b];
    }
    sh_prefix = (p8 << 8) | (unsigned)b;
    sh_remk = remk - cum;
  }
  __syncthreads();
  const unsigned T16 = sh_prefix;
  remk = sh_remk;

  if (tid == 0) { cnt_gt = 0; cnt_eq = 0; }
  __syncthreads();
  for (int e = tid; e < NBAND; e += 1024) {
    unsigned key = f2key(band[e]);
    unsigned k16 = key >> 16;
    if (k16 >= T16) {
      int i = e / MAXSPAN, d = e - i * MAXSPAN;
      int fi = i * S + i + d;
      if (k16 > T16) {
        int p = atomicAdd(&cnt_gt, 1);
        if (p < 1024) idxbuf[p] = fi;
      } else {
        int p = atomicAdd(&cnt_eq, 1);
        if (p < 256) { tkey[p] = key; tidx[p] = fi; }
      }
    }
  }
  __syncthreads();
  if (tid == 0) {
    int ngt = cnt_gt < 1024 ? cnt_gt : 1024;
    int ne = cnt_eq < 256 ? cnt_eq : 256;
    for (int a2 = 1; a2 < ne; a2++) {
      unsigned kv = tkey[a2]; int iv = tidx[a2];
      int b2 = a2 - 1;
      while (b2 >= 0 && (tkey[b2] < kv || (tkey[b2] == kv && tidx[b2] > iv))) {
        tkey[b2 + 1] = tkey[b2]; tidx[b2 + 1] = tidx[b2]; b2--;
      }
      tkey[b2 + 1] = kv; tidx[b2 + 1] = iv;
    }
    int take = remk < ne ? remk : ne;
    for (int q = 0; q < take; q++)
      if (ngt + q < 1024) idxbuf[ngt + q] = tidx[q];
  }
  __syncthreads();

  sb[tid] = (tid < MAXK) ? idxbuf[tid] : 0x7FFFFFFF;
  __syncthreads();
  for (int ksz = 2; ksz <= 1024; ksz <<= 1) {
    for (int jj = ksz >> 1; jj > 0; jj >>= 1) {
      int ixj = tid ^ jj;
      if (ixj > tid) {
        int a2 = sb[tid], b2 = sb[ixj];
        bool up = ((tid & ksz) == 0);
        if (up ? (a2 > b2) : (a2 < b2)) { sb[tid] = b2; sb[ixj] = a2; }
      }
      __syncthreads();
    }
  }
  if (tid < MAXK) {
    int fi = sb[tid];
    out[O_START + tid] = (float)(fi >> 12);
    out[O_END + tid]   = (float)(fi & 4095);
    out[O_MASK + tid]  = 1.0f;
  }

  // ---- cost finalize ----
  if (tid < G) {
    int gs = gold[2 * tid], ge = gold[2 * tid + 1];
    gcell[tid] = gs * MAXSPAN + (ge - gs);
  }
  __syncthreads();
  float tg = 0.0f, tj = 0.0f;
  if (tid < G) {
    int cell = gcell[tid];
    float x = band[cell];
    float p = 1.0f / (1.0f + expf(-x));
    tg = fmaxf(logf(p), -100.0f);
    bool first = true;
    for (int q = 0; q < tid; q++)
      if (gcell[q] == cell) { first = false; break; }
    if (first) tj = fmaxf(logf(1.0f - p), -100.0f);
  }
  float sg = block_reduce_1024(tg, redf);
  float sj = block_reduce_1024(tj, redf);
  if (tid == 0) {
    double junk = *jacc - (double)sj;   // exclude gold cells (set to 0 in reference)
    double cost = -((double)sg / (double)G) - (junk / BAND_COUNT);
    out[O_COST] = (float)cost;
  }
}

// ---------------- launch ----------------

extern "C" void kernel_launch(void* const* d_in, const int* in_sizes, int n_in,
                              void* d_out, int out_size, void* d_ws, size_t ws_size,
                              hipStream_t stream) {
  (void)in_sizes; (void)n_in; (void)out_size; (void)ws_size;
  const float* seq    = (const float*)d_in[0];
  const int*   gold   = (const int*)d_in[2];
  const float* W_sm   = (const float*)d_in[3];
  const float* b_sm   = (const float*)d_in[4];
  const float* g_sm   = (const float*)d_in[5];
  const float* be_sm  = (const float*)d_in[6];
  const float* W_em   = (const float*)d_in[7];
  const float* b_em   = (const float*)d_in[8];
  const float* g_em   = (const float*)d_in[9];
  const float* be_em  = (const float*)d_in[10];
  const float* w_st   = (const float*)d_in[11];
  const float* b_st   = (const float*)d_in[12];
  const float* w_en   = (const float*)d_in[13];
  const float* b_en   = (const float*)d_in[14];
  const float* W_s2e  = (const float*)d_in[15];
  const float* b_s2e  = (const float*)d_in[16];
  float* out = (float*)d_out;
  char* ws = (char*)d_ws;

  const size_t SZ_REP = (size_t)S * FF * 4;          // 50331648
  float*  bufS = (float*)(ws);                       // h_start f32 (gelu out, pre-LN)
  float*  bufE = (float*)(ws + SZ_REP);              // h_end f32 (gelu out, pre-LN)
  float*  bufT = (float*)(ws + 2 * SZ_REP);          // temp f32
  // R3: seq hi/lo tiled during GEMM1/2; reused as a3 (normalized start) hi/lo tiled
  char* R3 = ws + 3 * SZ_REP;
  unsigned short* seqhi = (unsigned short*)R3;
  unsigned short* seqlo = (unsigned short*)(R3 + (size_t)S * H * 2);
  unsigned short* a3hi  = (unsigned short*)R3;
  unsigned short* a3lo  = (unsigned short*)(R3 + (size_t)S * FF * 2);
  // R4: tiled weights. Phase 1: wb1/wb2 (H x FF). Phase 2: wb (FF x FF).
  char* R4 = ws + 4 * SZ_REP;
  const size_t SZ_W12 = (size_t)H * FF * 2;          // 6291456
  unsigned short* wb1hi = (unsigned short*)R4;
  unsigned short* wb1lo = (unsigned short*)(R4 + SZ_W12);
  unsigned short* wb2hi = (unsigned short*)(R4 + 2 * SZ_W12);
  unsigned short* wb2lo = (unsigned short*)(R4 + 3 * SZ_W12);
  unsigned short* wbhi = (unsigned short*)R4;
  unsigned short* wblo = (unsigned short*)(R4 + (size_t)FF * FF * 2);
  // R5: small buffers
  char* R5 = R4 + 2 * (size_t)FF * FF * 2;
  float*  band = (float*)R5;                          // NBAND f32
  double* jacc = (double*)(R5 + (size_t)NBAND * 4);   // 8-aligned
  float*  slog = (float*)(R5 + (size_t)NBAND * 4 + 64);
  float*  elog  = slog + S;
  float*  muS   = elog + S;
  float*  rstdS = muS + S;
  float*  muE   = rstdS + S;
  float*  rstdE = muE + S;
  float*  gwS   = rstdE + S;          // FF
  float*  gwE   = gwS + FF;           // FF
  float*  sums  = gwE + FF;           // 6*S

  dim3 gg(FF / 128, S / 128);        // (24, 32)
  dim3 gg2(FF / 128, S / 128, 2);    // fused GEMM1+2

  // prep: gw vectors, zero stats + jacc
  prep_kernel<<<96, 256, 0, stream>>>(g_sm, w_st, g_em, w_en, gwS, gwE, sums, jacc);
  // seq -> tiled hi/lo (M=S, K=H)
  pack_a_kernel<<<dim3(H / 32, S / 32), 256, 0, stream>>>(seq, seqhi, seqlo, H);
  // both H x FF weights -> tiled B^T hi/lo in one dispatch
  pack_bt_dual_kernel<<<dim3(H / 32, FF / 32, 2), 256, 0, stream>>>(W_sm, W_em,
                                                                    wb1hi, wb1lo, wb2hi, wb2lo, H, FF);
  // fused GEMM1+2 (gelu + row-stats epilogue)
  gemm_mfma_dual_kernel<<<gg2, 256, 0, stream>>>(seqhi, seqlo, wb1hi, wb1lo, wb2hi, wb2lo,
                                                 b_sm, b_em, bufS, bufE, gwS, gwE, sums, FF, H);
  // LN finalize: mu/rstd/logits from sums
  ln_finalize_kernel<<<dim3(S / 256, 2), 256, 0, stream>>>(sums, gwS, be_sm, w_st, b_st,
                                                           gwE, be_em, w_en, b_en,
                                                           muS, rstdS, slog, muE, rstdE, elog);
  // start_reps tiled hi/lo via fused LN pack ; W_s2e tiled ; GEMM3
  pack_ln_a_kernel<<<dim3(FF / 32, S / 32), 256, 0, stream>>>(bufS, muS, rstdS, g_sm, be_sm, a3hi, a3lo, FF);
  pack_bt_kernel<<<dim3(FF / 32, FF / 32), 256, 0, stream>>>(W_s2e, wbhi, wblo, FF, FF);
  gemm_mfma_kernel<<<gg, 256, 0, stream>>>(a3hi, a3lo, wbhi, wblo, b_s2e, bufT, FF, FF);

  // band joint with inline E-LayerNorm + fused junk-cost accumulation
  band_joint_kernel<<<S / 16, 256, 0, stream>>>(bufT, bufE, muE, rstdE, g_em, be_em,
                                                slog, elog, band, jacc);

  // top-k + cost finalize (gold correction w/ dedupe)
  topk_finalize_kernel<<<1, 1024, 0, stream>>>(band, gold, jacc, out);

  hipMemcpyAsync(out + O_SEQ, seq, (size_t)S * H * 4, hipMemcpyDeviceToDevice, stream);
}

// Round 7
// 824.216 us; speedup vs baseline: 1.0372x; 1.0372x over previous
//
#include <hip/hip_runtime.h>
#include <math.h>

#define S 4096
#define H 1024
#define FF 3072
#define G 100
#define MAXSPAN 30
#define MAXK 819
#define NBAND (S * MAXSPAN)   // 122880 slots, 122445 valid
#define BAND_COUNT 122445.0

// out layout (float32)
#define O_START 0
#define O_END   819
#define O_MASK  1638
#define O_SEQ   2457
#define O_COST  (2457 + S * H)   // 4196761

typedef __bf16 bf16x8 __attribute__((ext_vector_type(8)));
typedef float f32x16 __attribute__((ext_vector_type(16)));

// ---------------- helpers ----------------

__device__ __forceinline__ float block_reduce_256(float x, volatile float* red) {
  #pragma unroll
  for (int off = 32; off > 0; off >>= 1) x += __shfl_down(x, off, 64);
  int wid = threadIdx.x >> 6;
  int lane = threadIdx.x & 63;
  __syncthreads();
  if (lane == 0) red[wid] = x;
  __syncthreads();
  return red[0] + red[1] + red[2] + red[3];
}

__device__ __forceinline__ float block_reduce_1024(float x, volatile float* red) {
  #pragma unroll
  for (int off = 32; off > 0; off >>= 1) x += __shfl_down(x, off, 64);
  int wid = threadIdx.x >> 6;   // 0..15
  int lane = threadIdx.x & 63;
  __syncthreads();
  if (lane == 0) red[wid] = x;
  __syncthreads();
  float s = 0.f;
  #pragma unroll
  for (int q = 0; q < 16; q++) s += red[q];
  return s;
}

__device__ __forceinline__ unsigned f2key(float f) {
  unsigned b = __float_as_uint(f);
  return (b & 0x80000000u) ? ~b : (b | 0x80000000u);
}

__device__ __forceinline__ unsigned short bf16_rne(float x) {
  unsigned u = __float_as_uint(x);
  unsigned r = ((u >> 16) & 1u) + 0x7FFFu;
  return (unsigned short)((u + r) >> 16);
}

__device__ __forceinline__ void split2(float x, unsigned short& h, unsigned short& l) {
  h = bf16_rne(x);
  float hf = __uint_as_float(((unsigned)h) << 16);
  l = bf16_rne(x - hf);
}

__device__ __forceinline__ void gld16(const void* g, void* l) {
  __builtin_amdgcn_global_load_lds(
      (const __attribute__((address_space(1))) unsigned int*)g,
      (__attribute__((address_space(3))) unsigned int*)l, 16, 0, 0);
}

// ---------------- pack kernels: f32 -> hi/lo bf16, tiled [panel][kq][r][8] ----------------
// tiled element offset = panel*(128*K) + kq*1024 + r*8 + s   (panel = row/128, kq = k/8)

__global__ __launch_bounds__(256) void pack_a_kernel(const float* __restrict__ A,
                                                     unsigned short* __restrict__ hi,
                                                     unsigned short* __restrict__ lo,
                                                     int K) {
  __shared__ float tile[32][33];
  const int t = threadIdx.x;
  const int tx = t & 31, ty8 = t >> 5;
  const int k0 = blockIdx.x * 32, r0 = blockIdx.y * 32;
  #pragma unroll
  for (int r = ty8; r < 32; r += 8)
    tile[r][tx] = A[(size_t)(r0 + r) * K + k0 + tx];
  __syncthreads();
  if (t < 128) {
    const int kql = t >> 5;
    const int rl = t & 31;
    unsigned short h8[8], l8[8];
    #pragma unroll
    for (int s = 0; s < 8; s++) split2(tile[rl][kql * 8 + s], h8[s], l8[s]);
    const size_t panel = (size_t)(r0 >> 7);
    const int rloc = (r0 & 127) + rl;
    const size_t off = panel * (size_t)(128 * K) + (size_t)(k0 / 8 + kql) * 1024 + (size_t)rloc * 8;
    *(uint4*)(hi + off) = *(const uint4*)h8;
    *(uint4*)(lo + off) = *(const uint4*)l8;
  }
}

// A-side with fused LayerNorm: val = (A - mu[row]) * rstd[row] * g[k] + beta[k]
__global__ __launch_bounds__(256) void pack_ln_a_kernel(const float* __restrict__ A,
                                                        const float* __restrict__ mu,
                                                        const float* __restrict__ rstd,
                                                        const float* __restrict__ g,
                                                        const float* __restrict__ beta,
                                                        unsigned short* __restrict__ hi,
                                                        unsigned short* __restrict__ lo,
                                                        int K) {
  __shared__ float tile[32][33];
  const int t = threadIdx.x;
  const int tx = t & 31, ty8 = t >> 5;
  const int k0 = blockIdx.x * 32, r0 = blockIdx.y * 32;
  #pragma unroll
  for (int r = ty8; r < 32; r += 8)
    tile[r][tx] = A[(size_t)(r0 + r) * K + k0 + tx];
  __syncthreads();
  if (t < 128) {
    const int kql = t >> 5;
    const int rl = t & 31;
    const int row = r0 + rl;
    const float m = mu[row], rs = rstd[row];
    float4 g0 = *(const float4*)(g + k0 + kql * 8);
    float4 g1 = *(const float4*)(g + k0 + kql * 8 + 4);
    float4 b0 = *(const float4*)(beta + k0 + kql * 8);
    float4 b1 = *(const float4*)(beta + k0 + kql * 8 + 4);
    float gv[8] = {g0.x, g0.y, g0.z, g0.w, g1.x, g1.y, g1.z, g1.w};
    float bv[8] = {b0.x, b0.y, b0.z, b0.w, b1.x, b1.y, b1.z, b1.w};
    unsigned short h8[8], l8[8];
    #pragma unroll
    for (int s = 0; s < 8; s++) {
      float v = (tile[rl][kql * 8 + s] - m) * rs * gv[s] + bv[s];
      split2(v, h8[s], l8[s]);
    }
    const size_t panel = (size_t)(r0 >> 7);
    const int rloc = (r0 & 127) + rl;
    const size_t off = panel * (size_t)(128 * K) + (size_t)(k0 / 8 + kql) * 1024 + (size_t)rloc * 8;
    *(uint4*)(hi + off) = *(const uint4*)h8;
    *(uint4*)(lo + off) = *(const uint4*)l8;
  }
}

__device__ __forceinline__ void pack_bt_body(const float* __restrict__ W,
                                             unsigned short* __restrict__ hi,
                                             unsigned short* __restrict__ lo,
                                             int K, int N) {
  __shared__ float tile[32][33];   // tile[k_local][n_local]
  const int t = threadIdx.x;
  const int tx = t & 31, ty8 = t >> 5;
  const int k0 = blockIdx.x * 32, n0 = blockIdx.y * 32;
  #pragma unroll
  for (int r = ty8; r < 32; r += 8)
    tile[r][tx] = W[(size_t)(k0 + r) * N + n0 + tx];
  __syncthreads();
  if (t < 128) {
    const int kql = t >> 5;
    const int nl = t & 31;
    unsigned short h8[8], l8[8];
    #pragma unroll
    for (int s = 0; s < 8; s++) split2(tile[kql * 8 + s][nl], h8[s], l8[s]);
    const size_t panel = (size_t)(n0 >> 7);
    const int nloc = (n0 & 127) + nl;
    const size_t off = panel * (size_t)(128 * K) + (size_t)(k0 / 8 + kql) * 1024 + (size_t)nloc * 8;
    *(uint4*)(hi + off) = *(const uint4*)h8;
    *(uint4*)(lo + off) = *(const uint4*)l8;
  }
}

__global__ __launch_bounds__(256) void pack_bt_kernel(const float* __restrict__ W,
                                                      unsigned short* __restrict__ hi,
                                                      unsigned short* __restrict__ lo,
                                                      int K, int N) {
  pack_bt_body(W, hi, lo, K, N);
}

// both H x FF weights in one dispatch
__global__ __launch_bounds__(256) void pack_bt_dual_kernel(const float* __restrict__ W1,
                                                           const float* __restrict__ W2,
                                                           unsigned short* __restrict__ h1,
                                                           unsigned short* __restrict__ l1,
                                                           unsigned short* __restrict__ h2,
                                                           unsigned short* __restrict__ l2,
                                                           int K, int N) {
  if (blockIdx.z == 0) pack_bt_body(W1, h1, l1, K, N);
  else                 pack_bt_body(W2, h2, l2, K, N);
}

// ---------------- MFMA GEMM core (32x32x16, 3-product split, double-buffered LDS) ----------------
// K-loop: one barrier per K-step; stage(next) issued right after barrier so the
// global_load_lds latency is hidden behind the current step's ds_read+MFMA.

template <int EPI>
__device__ __forceinline__ void gemm_body(const char* cAh, const char* cAl,
                                          const char* cBh, const char* cBl,
                                          const float* __restrict__ bias,
                                          float* __restrict__ C,
                                          int bm, int bn, int N, int K,
                                          char* smem) {
  const int tid = threadIdx.x;
  const int lane = tid & 63;
  const int wid = __builtin_amdgcn_readfirstlane(tid >> 6);
  const int wm = wid >> 1, wn = wid & 1;
  const int lb = lane * 16;
  const int ldsq = wid * 2048;

  const int khalf = lane >> 5;
  const int r31 = lane & 31;
  const int abase = khalf * 2048 + (wm * 64 + r31) * 16;
  const int bbase = khalf * 2048 + (wn * 64 + r31) * 16;

  f32x16 acc[2][2];
  #pragma unroll
  for (int a = 0; a < 2; a++)
    #pragma unroll
    for (int b = 0; b < 2; b++)
      #pragma unroll
      for (int r = 0; r < 16; r++) acc[a][b][r] = 0.0f;

  // stage K-block k0 into buffer `buf`
  auto stage = [&](int buf, int k0) {
    const size_t qb = (size_t)((k0 >> 3) + wid) * 2048 + lb;
    char* sbuf = smem + buf * 32768 + ldsq;
    gld16(cAh + qb,        sbuf +     0);
    gld16(cAh + qb + 1024, sbuf +     0 + 1024);
    gld16(cAl + qb,        sbuf +  8192);
    gld16(cAl + qb + 1024, sbuf +  8192 + 1024);
    gld16(cBh + qb,        sbuf + 16384);
    gld16(cBh + qb + 1024, sbuf + 16384 + 1024);
    gld16(cBl + qb,        sbuf + 24576);
    gld16(cBl + qb + 1024, sbuf + 24576 + 1024);
  };

  stage(0, 0);
  for (int k0 = 0; k0 < K; k0 += 32) {
    const int cur = (k0 >> 5) & 1;
    __syncthreads();   // drains cur-buffer loads (issued one compute-phase ago)
    if (k0 + 32 < K) stage(cur ^ 1, k0 + 32);
    const char* sm = smem + cur * 32768;

    bf16x8 ah[2][2], al[2][2], bh[2][2], bl[2][2];
    #pragma unroll
    for (int ks = 0; ks < 2; ks++) {
      #pragma unroll
      for (int mt = 0; mt < 2; mt++) {
        ah[ks][mt] = *(const bf16x8*)(sm +     0 + ks * 4096 + abase + mt * 512);
        al[ks][mt] = *(const bf16x8*)(sm +  8192 + ks * 4096 + abase + mt * 512);
      }
      #pragma unroll
      for (int nt = 0; nt < 2; nt++) {
        bh[ks][nt] = *(const bf16x8*)(sm + 16384 + ks * 4096 + bbase + nt * 512);
        bl[ks][nt] = *(const bf16x8*)(sm + 24576 + ks * 4096 + bbase + nt * 512);
      }
    }
    #pragma unroll
    for (int ks = 0; ks < 2; ks++)
      #pragma unroll
      for (int mt = 0; mt < 2; mt++)
        #pragma unroll
        for (int nt = 0; nt < 2; nt++) {
          acc[mt][nt] = __builtin_amdgcn_mfma_f32_32x32x16_bf16(ah[ks][mt], bh[ks][nt], acc[mt][nt], 0, 0, 0);
          acc[mt][nt] = __builtin_amdgcn_mfma_f32_32x32x16_bf16(al[ks][mt], bh[ks][nt], acc[mt][nt], 0, 0, 0);
          acc[mt][nt] = __builtin_amdgcn_mfma_f32_32x32x16_bf16(ah[ks][mt], bl[ks][nt], acc[mt][nt], 0, 0, 0);
        }
  }

  // epilogue: col=lane&31, row=(reg&3)+8*(reg>>2)+4*khalf
  #pragma unroll
  for (int mt = 0; mt < 2; mt++) {
    #pragma unroll
    for (int nt = 0; nt < 2; nt++) {
      const int colg = bn + wn * 64 + nt * 32 + r31;
      const float bb = bias[colg];
      #pragma unroll
      for (int reg = 0; reg < 16; reg++) {
        const int rowl = (reg & 3) + 8 * (reg >> 2) + 4 * khalf;
        const int rowg = bm + wm * 64 + mt * 32 + rowl;
        float v = acc[mt][nt][reg] + bb;
        if (EPI == 1) v = 0.5f * v * (1.0f + erff(v * 0.70710678118654752f));
        C[(size_t)rowg * N + colg] = v;
      }
    }
  }
}

// GEMM3: single output
__global__ __launch_bounds__(256) void gemm_mfma_kernel(const unsigned short* __restrict__ Ahi,
                                                        const unsigned short* __restrict__ Alo,
                                                        const unsigned short* __restrict__ Bhi,
                                                        const unsigned short* __restrict__ Blo,
                                                        const float* __restrict__ bias,
                                                        float* __restrict__ C,
                                                        int N, int K) {
  __shared__ __align__(16) char smem[65536];
  const size_t panAb = (size_t)blockIdx.y * (size_t)(128 * K) * 2;
  const size_t panBb = (size_t)blockIdx.x * (size_t)(128 * K) * 2;
  gemm_body<0>((const char*)Ahi + panAb, (const char*)Alo + panAb,
               (const char*)Bhi + panBb, (const char*)Blo + panBb,
               bias, C, blockIdx.y * 128, blockIdx.x * 128, N, K, smem);
}

// GEMM1+2 fused: blockIdx.z picks branch (same A), gelu epilogue
__global__ __launch_bounds__(256) void gemm_mfma_dual_kernel(const unsigned short* __restrict__ Ahi,
                                                             const unsigned short* __restrict__ Alo,
                                                             const unsigned short* __restrict__ B1hi,
                                                             const unsigned short* __restrict__ B1lo,
                                                             const unsigned short* __restrict__ B2hi,
                                                             const unsigned short* __restrict__ B2lo,
                                                             const float* __restrict__ bias1,
                                                             const float* __restrict__ bias2,
                                                             float* __restrict__ C1,
                                                             float* __restrict__ C2,
                                                             int N, int K) {
  __shared__ __align__(16) char smem[65536];
  const int zb = blockIdx.z;
  const unsigned short* Bhi = zb ? B2hi : B1hi;
  const unsigned short* Blo = zb ? B2lo : B1lo;
  const float* bias = zb ? bias2 : bias1;
  float* C = zb ? C2 : C1;
  const size_t panAb = (size_t)blockIdx.y * (size_t)(128 * K) * 2;
  const size_t panBb = (size_t)blockIdx.x * (size_t)(128 * K) * 2;
  gemm_body<1>((const char*)Ahi + panAb, (const char*)Alo + panAb,
               (const char*)Bhi + panBb, (const char*)Blo + panBb,
               bias, C, blockIdx.y * 128, blockIdx.x * 128, N, K, smem);
}

// ---------------- LN stats + logit (no writeback), both branches ----------------
// grid (S, 2): y=0 start branch, y=1 end branch

__global__ __launch_bounds__(256) void ln_stats_kernel(const float* __restrict__ HbS,
                                                       const float* __restrict__ HbE,
                                                       const float* __restrict__ gS,
                                                       const float* __restrict__ betaS,
                                                       const float* __restrict__ wS,
                                                       const float* __restrict__ bS,
                                                       const float* __restrict__ gE,
                                                       const float* __restrict__ betaE,
                                                       const float* __restrict__ wE,
                                                       const float* __restrict__ bE,
                                                       float* __restrict__ slog,
                                                       float* __restrict__ elog,
                                                       float* __restrict__ muS,
                                                       float* __restrict__ rstdS,
                                                       float* __restrict__ muE,
                                                       float* __restrict__ rstdE) {
  __shared__ float red[4];
  const int row = blockIdx.x, tid = threadIdx.x;
  const int br = blockIdx.y;
  const float* Hb = br ? HbE : HbS;
  const float* g = br ? gE : gS;
  const float* beta = br ? betaE : betaS;
  const float* w = br ? wE : wS;
  const float* bsc = br ? bE : bS;
  const float* h = Hb + (size_t)row * FF;

  float4 v[3];
  float s = 0.0f;
  #pragma unroll
  for (int t = 0; t < 3; t++) {
    v[t] = *(const float4*)(h + tid * 4 + t * 1024);
    s += v[t].x + v[t].y + v[t].z + v[t].w;
  }
  float mu = block_reduce_256(s, red) * (1.0f / (float)FF);

  float s2 = 0.0f;
  #pragma unroll
  for (int t = 0; t < 3; t++) {
    float dx = v[t].x - mu, dy = v[t].y - mu, dz = v[t].z - mu, dw = v[t].w - mu;
    s2 += dx * dx + dy * dy + dz * dz + dw * dw;
  }
  float var = block_reduce_256(s2, red) * (1.0f / (float)FF);
  float rstd = rsqrtf(var + 1e-5f);

  float dot = 0.0f;
  #pragma unroll
  for (int t = 0; t < 3; t++) {
    int idx = tid * 4 + t * 1024;
    float4 gv = *(const float4*)(g + idx);
    float4 bv = *(const float4*)(beta + idx);
    float4 wv = *(const float4*)(w + idx);
    float rx = (v[t].x - mu) * rstd * gv.x + bv.x;
    float ry = (v[t].y - mu) * rstd * gv.y + bv.y;
    float rz = (v[t].z - mu) * rstd * gv.z + bv.z;
    float rw = (v[t].w - mu) * rstd * gv.w + bv.w;
    dot += rx * wv.x + ry * wv.y + rz * wv.z + rw * wv.w;
  }
  float dt = block_reduce_256(dot, red);
  if (tid == 0) {
    if (br) { elog[row] = dt + bsc[0]; muE[row] = mu; rstdE[row] = rstd; }
    else    { slog[row] = dt + bsc[0]; muS[row] = mu; rstdS[row] = rstd; }
  }
}

// ---------------- band joint (tiled, LDS E-chunk, inline E-LayerNorm, fused junk sum) ----------------

__global__ __launch_bounds__(256) void band_joint_kernel(const float* __restrict__ T,
                                                         const float* __restrict__ Eraw,
                                                         const float* __restrict__ muE,
                                                         const float* __restrict__ rstdE,
                                                         const float* __restrict__ gE,
                                                         const float* __restrict__ betaE,
                                                         const float* __restrict__ sl,
                                                         const float* __restrict__ el,
                                                         float* __restrict__ band,
                                                         double* __restrict__ jacc) {
  __shared__ float Elds[45][260];   // 260 = 256 + 4 pad
  __shared__ float red[4];
  const int t = threadIdx.x;
  const int bx = blockIdx.x;
  const int sbx = (bx & 7) * 32 + (bx >> 3);   // XCD-locality swizzle (perf heuristic)
  const int i0 = sbx * 16;
  const int r_l = t >> 4, c = t & 15;

  float accd[MAXSPAN];
  #pragma unroll
  for (int d = 0; d < MAXSPAN; d++) accd[d] = 0.0f;

  for (int k0 = 0; k0 < FF; k0 += 256) {
    const float* trow = T + (size_t)(i0 + r_l) * FF + k0 + c * 16;
    float4 tv0 = *(const float4*)(trow + 0);
    float4 tv1 = *(const float4*)(trow + 4);
    float4 tv2 = *(const float4*)(trow + 8);
    float4 tv3 = *(const float4*)(trow + 12);
    __syncthreads();
    for (int rr = t >> 6; rr < 45; rr += 4) {
      int gr = i0 + rr;
      int cc = (t & 63) * 4;
      float4 rv = {0.f, 0.f, 0.f, 0.f};
      if (gr < S) {
        float4 ev = *(const float4*)(Eraw + (size_t)gr * FF + k0 + cc);
        float m = muE[gr], rs = rstdE[gr];
        float4 gv = *(const float4*)(gE + k0 + cc);
        float4 bv = *(const float4*)(betaE + k0 + cc);
        rv.x = (ev.x - m) * rs * gv.x + bv.x;
        rv.y = (ev.y - m) * rs * gv.y + bv.y;
        rv.z = (ev.z - m) * rs * gv.z + bv.z;
        rv.w = (ev.w - m) * rs * gv.w + bv.w;
      }
      *(float4*)&Elds[rr][cc] = rv;
    }
    __syncthreads();
    #pragma unroll
    for (int d = 0; d < MAXSPAN; d++) {
      const float* er = &Elds[r_l + d][c * 16];
      float4 e0 = *(const float4*)(er + 0);
      float4 e1 = *(const float4*)(er + 4);
      float4 e2 = *(const float4*)(er + 8);
      float4 e3 = *(const float4*)(er + 12);
      accd[d] += tv0.x * e0.x + tv0.y * e0.y + tv0.z * e0.z + tv0.w * e0.w
               + tv1.x * e1.x + tv1.y * e1.y + tv1.z * e1.z + tv1.w * e1.w
               + tv2.x * e2.x + tv2.y * e2.y + tv2.z * e2.z + tv2.w * e2.w
               + tv3.x * e3.x + tv3.y * e3.y + tv3.z * e3.z + tv3.w * e3.w;
    }
  }

  const int i = i0 + r_l;
  const float my_sl = sl[i];
  float jsum = 0.0f;
  #pragma unroll
  for (int d = 0; d < MAXSPAN; d++) {
    float v = accd[d];
    v += __shfl_down(v, 8, 16);
    v += __shfl_down(v, 4, 16);
    v += __shfl_down(v, 2, 16);
    v += __shfl_down(v, 1, 16);
    if (c == 0) {
      int j = i + d;
      if (j < S) {
        float vv = v + my_sl + el[j];
        vv = fminf(fmaxf(vv, -10000.0f), 10000.0f);
        band[i * MAXSPAN + d] = vv;
        float p = 1.0f / (1.0f + expf(-vv));
        jsum += fmaxf(logf(1.0f - p), -100.0f);
      } else {
        band[i * MAXSPAN + d] = -1e30f;
      }
    }
  }
  float tot = block_reduce_256(jsum, red);
  if (t == 0) atomicAdd(jacc, (double)tot);
}

// ---------------- top-k + cost finalize (single block) ----------------

__global__ __launch_bounds__(1024) void topk_finalize_kernel(const float* __restrict__ band,
                                                             const int* __restrict__ gold,
                                                             const double* __restrict__ jacc,
                                                             float* __restrict__ out) {
  __shared__ int hist[256];
  __shared__ unsigned sh_prefix;
  __shared__ int sh_remk;
  __shared__ int idxbuf[1024];
  __shared__ unsigned tkey[256];
  __shared__ int tidx[256];
  __shared__ int cnt_gt, cnt_eq;
  __shared__ int sb[1024];
  __shared__ int gcell[G];
  __shared__ float redf[16];
  const int tid = threadIdx.x;

  // pass 0: top 8 bits
  if (tid < 256) hist[tid] = 0;
  __syncthreads();
  for (int e = tid; e < NBAND; e += 1024)
    atomicAdd(&hist[f2key(band[e]) >> 24], 1);
  __syncthreads();
  if (tid == 0) {
    int cum = 0, b = 255;
    for (; b > 0; b--) {
      if (cum + hist[b] >= MAXK) break;
      cum += hist[b];
    }
    sh_prefix = (unsigned)b;
    sh_remk = MAXK - cum;
  }
  __syncthreads();
  const unsigned p8 = sh_prefix;
  int remk = sh_remk;
  __syncthreads();

  // pass 1: bits 23..16 within prefix
  if (tid < 256) hist[tid] = 0;
  __syncthreads();
  for (int e = tid; e < NBAND; e += 1024) {
    unsigned key = f2key(band[e]);
    if ((key >> 24) == p8) atomicAdd(&hist[(key >> 16) & 255], 1);
  }
  __syncthreads();
  if (tid == 0) {
    int cum = 0, b = 255;
    for (; b > 0; b--) {
      if (cum + hist[b] >= remk) break;
      cum += hist[b];
    }
    sh_prefix = (p8 << 8) | (unsigned)b;
    sh_remk = remk - cum;
  }
  __syncthreads();
  const unsigned T16 = sh_prefix;
  remk = sh_remk;

  if (tid == 0) { cnt_gt = 0; cnt_eq = 0; }
  __syncthreads();
  for (int e = tid; e < NBAND; e += 1024) {
    unsigned key = f2key(band[e]);
    unsigned k16 = key >> 16;
    if (k16 >= T16) {
      int i = e / MAXSPAN, d = e - i * MAXSPAN;
      int fi = i * S + i + d;
      if (k16 > T16) {
        int p = atomicAdd(&cnt_gt, 1);
        if (p < 1024) idxbuf[p] = fi;
      } else {
        int p = atomicAdd(&cnt_eq, 1);
        if (p < 256) { tkey[p] = key; tidx[p] = fi; }
      }
    }
  }
  __syncthreads();
  if (tid == 0) {
    int ngt = cnt_gt < 1024 ? cnt_gt : 1024;
    int ne = cnt_eq < 256 ? cnt_eq : 256;
    for (int a2 = 1; a2 < ne; a2++) {
      unsigned kv = tkey[a2]; int iv = tidx[a2];
      int b2 = a2 - 1;
      while (b2 >= 0 && (tkey[b2] < kv || (tkey[b2] == kv && tidx[b2] > iv))) {
        tkey[b2 + 1] = tkey[b2]; tidx[b2 + 1] = tidx[b2]; b2--;
      }
      tkey[b2 + 1] = kv; tidx[b2 + 1] = iv;
    }
    int take = remk < ne ? remk : ne;
    for (int q = 0; q < take; q++)
      if (ngt + q < 1024) idxbuf[ngt + q] = tidx[q];
  }
  __syncthreads();

  sb[tid] = (tid < MAXK) ? idxbuf[tid] : 0x7FFFFFFF;
  __syncthreads();
  for (int ksz = 2; ksz <= 1024; ksz <<= 1) {
    for (int jj = ksz >> 1; jj > 0; jj >>= 1) {
      int ixj = tid ^ jj;
      if (ixj > tid) {
        int a2 = sb[tid], b2 = sb[ixj];
        bool up = ((tid & ksz) == 0);
        if (up ? (a2 > b2) : (a2 < b2)) { sb[tid] = b2; sb[ixj] = a2; }
      }
      __syncthreads();
    }
  }
  if (tid < MAXK) {
    int fi = sb[tid];
    out[O_START + tid] = (float)(fi >> 12);
    out[O_END + tid]   = (float)(fi & 4095);
    out[O_MASK + tid]  = 1.0f;
  }

  // ---- cost finalize ----
  if (tid < G) {
    int gs = gold[2 * tid], ge = gold[2 * tid + 1];
    gcell[tid] = gs * MAXSPAN + (ge - gs);
  }
  __syncthreads();
  float tg = 0.0f, tj = 0.0f;
  if (tid < G) {
    int cell = gcell[tid];
    float x = band[cell];
    float p = 1.0f / (1.0f + expf(-x));
    tg = fmaxf(logf(p), -100.0f);
    bool first = true;
    for (int q = 0; q < tid; q++)
      if (gcell[q] == cell) { first = false; break; }
    if (first) tj = fmaxf(logf(1.0f - p), -100.0f);
  }
  float sg = block_reduce_1024(tg, redf);
  float sj = block_reduce_1024(tj, redf);
  if (tid == 0) {
    double junk = *jacc - (double)sj;   // exclude gold cells (set to 0 in reference)
    double cost = -((double)sg / (double)G) - (junk / BAND_COUNT);
    out[O_COST] = (float)cost;
  }
}

// ---------------- launch ----------------

extern "C" void kernel_launch(void* const* d_in, const int* in_sizes, int n_in,
                              void* d_out, int out_size, void* d_ws, size_t ws_size,
                              hipStream_t stream) {
  (void)in_sizes; (void)n_in; (void)out_size; (void)ws_size;
  const float* seq    = (const float*)d_in[0];
  const int*   gold   = (const int*)d_in[2];
  const float* W_sm   = (const float*)d_in[3];
  const float* b_sm   = (const float*)d_in[4];
  const float* g_sm   = (const float*)d_in[5];
  const float* be_sm  = (const float*)d_in[6];
  const float* W_em   = (const float*)d_in[7];
  const float* b_em   = (const float*)d_in[8];
  const float* g_em   = (const float*)d_in[9];
  const float* be_em  = (const float*)d_in[10];
  const float* w_st   = (const float*)d_in[11];
  const float* b_st   = (const float*)d_in[12];
  const float* w_en   = (const float*)d_in[13];
  const float* b_en   = (const float*)d_in[14];
  const float* W_s2e  = (const float*)d_in[15];
  const float* b_s2e  = (const float*)d_in[16];
  float* out = (float*)d_out;
  char* ws = (char*)d_ws;

  const size_t SZ_REP = (size_t)S * FF * 4;          // 50331648
  float*  bufS = (float*)(ws);                       // h_start f32 (gelu out, pre-LN)
  float*  bufE = (float*)(ws + SZ_REP);              // h_end f32 (gelu out, pre-LN)
  float*  bufT = (float*)(ws + 2 * SZ_REP);          // temp f32
  // R3: seq hi/lo tiled during GEMM1/2; reused as a3 (normalized start) hi/lo tiled
  char* R3 = ws + 3 * SZ_REP;
  unsigned short* seqhi = (unsigned short*)R3;
  unsigned short* seqlo = (unsigned short*)(R3 + (size_t)S * H * 2);
  unsigned short* a3hi  = (unsigned short*)R3;
  unsigned short* a3lo  = (unsigned short*)(R3 + (size_t)S * FF * 2);
  // R4: tiled weights. Phase 1: wb1/wb2 (H x FF). Phase 2: wb (FF x FF).
  char* R4 = ws + 4 * SZ_REP;
  const size_t SZ_W12 = (size_t)H * FF * 2;          // 6291456
  unsigned short* wb1hi = (unsigned short*)R4;
  unsigned short* wb1lo = (unsigned short*)(R4 + SZ_W12);
  unsigned short* wb2hi = (unsigned short*)(R4 + 2 * SZ_W12);
  unsigned short* wb2lo = (unsigned short*)(R4 + 3 * SZ_W12);
  unsigned short* wbhi = (unsigned short*)R4;
  unsigned short* wblo = (unsigned short*)(R4 + (size_t)FF * FF * 2);
  // R5: small buffers
  char* R5 = R4 + 2 * (size_t)FF * FF * 2;
  float*  band = (float*)R5;                          // NBAND f32
  double* jacc = (double*)(R5 + (size_t)NBAND * 4);   // 8-aligned
  float*  slog = (float*)(R5 + (size_t)NBAND * 4 + 64);
  float*  elog  = slog + S;
  float*  muS   = elog + S;
  float*  rstdS = muS + S;
  float*  muE   = rstdS + S;
  float*  rstdE = muE + S;

  hipMemsetAsync(jacc, 0, 8, stream);

  dim3 gg(FF / 128, S / 128);        // (24, 32)
  dim3 gg2(FF / 128, S / 128, 2);    // fused GEMM1+2

  // seq -> tiled hi/lo (M=S, K=H)
  pack_a_kernel<<<dim3(H / 32, S / 32), 256, 0, stream>>>(seq, seqhi, seqlo, H);
  // both H x FF weights -> tiled B^T hi/lo in one dispatch
  pack_bt_dual_kernel<<<dim3(H / 32, FF / 32, 2), 256, 0, stream>>>(W_sm, W_em,
                                                                    wb1hi, wb1lo, wb2hi, wb2lo, H, FF);
  // fused GEMM1+2 (gelu epilogue, dbuf)
  gemm_mfma_dual_kernel<<<gg2, 256, 0, stream>>>(seqhi, seqlo, wb1hi, wb1lo, wb2hi, wb2lo,
                                                 b_sm, b_em, bufS, bufE, FF, H);
  // LN stats + logits for both branches, no writeback
  ln_stats_kernel<<<dim3(S, 2), 256, 0, stream>>>(bufS, bufE, g_sm, be_sm, w_st, b_st,
                                                  g_em, be_em, w_en, b_en,
                                                  slog, elog, muS, rstdS, muE, rstdE);
  // start_reps tiled hi/lo via fused LN pack ; W_s2e tiled ; GEMM3 (dbuf)
  pack_ln_a_kernel<<<dim3(FF / 32, S / 32), 256, 0, stream>>>(bufS, muS, rstdS, g_sm, be_sm, a3hi, a3lo, FF);
  pack_bt_kernel<<<dim3(FF / 32, FF / 32), 256, 0, stream>>>(W_s2e, wbhi, wblo, FF, FF);
  gemm_mfma_kernel<<<gg, 256, 0, stream>>>(a3hi, a3lo, wbhi, wblo, b_s2e, bufT, FF, FF);

  // band joint with inline E-LayerNorm + fused junk-cost accumulation
  band_joint_kernel<<<S / 16, 256, 0, stream>>>(bufT, bufE, muE, rstdE, g_em, be_em,
                                                slog, elog, band, jacc);

  // top-k + cost finalize (gold correction w/ dedupe)
  topk_finalize_kernel<<<1, 1024, 0, stream>>>(band, gold, jacc, out);

  hipMemcpyAsync(out + O_SEQ, seq, (size_t)S * H * 4, hipMemcpyDeviceToDevice, stream);
}

// Round 8
// 796.182 us; speedup vs baseline: 1.0737x; 1.0352x over previous
//
#include <hip/hip_runtime.h>
#include <math.h>

#define S 4096
#define H 1024
#define FF 3072
#define G 100
#define MAXSPAN 30
#define MAXK 819
#define NBAND (S * MAXSPAN)   // 122880 slots, 122445 valid
#define BAND_COUNT 122445.0

// out layout (float32)
#define O_START 0
#define O_END   819
#define O_MASK  1638
#define O_SEQ   2457
#define O_COST  (2457 + S * H)   // 4196761

typedef __bf16 bf16x8 __attribute__((ext_vector_type(8)));
typedef float f32x16 __attribute__((ext_vector_type(16)));

// ---------------- helpers ----------------

__device__ __forceinline__ float block_reduce_256(float x, volatile float* red) {
  #pragma unroll
  for (int off = 32; off > 0; off >>= 1) x += __shfl_down(x, off, 64);
  int wid = threadIdx.x >> 6;
  int lane = threadIdx.x & 63;
  __syncthreads();
  if (lane == 0) red[wid] = x;
  __syncthreads();
  return red[0] + red[1] + red[2] + red[3];
}

__device__ __forceinline__ float block_reduce_1024(float x, volatile float* red) {
  #pragma unroll
  for (int off = 32; off > 0; off >>= 1) x += __shfl_down(x, off, 64);
  int wid = threadIdx.x >> 6;   // 0..15
  int lane = threadIdx.x & 63;
  __syncthreads();
  if (lane == 0) red[wid] = x;
  __syncthreads();
  float s = 0.f;
  #pragma unroll
  for (int q = 0; q < 16; q++) s += red[q];
  return s;
}

__device__ __forceinline__ unsigned f2key(float f) {
  unsigned b = __float_as_uint(f);
  return (b & 0x80000000u) ? ~b : (b | 0x80000000u);
}

__device__ __forceinline__ unsigned short bf16_rne(float x) {
  unsigned u = __float_as_uint(x);
  unsigned r = ((u >> 16) & 1u) + 0x7FFFu;
  return (unsigned short)((u + r) >> 16);
}

__device__ __forceinline__ void split2(float x, unsigned short& h, unsigned short& l) {
  h = bf16_rne(x);
  float hf = __uint_as_float(((unsigned)h) << 16);
  l = bf16_rne(x - hf);
}

__device__ __forceinline__ void gld16(const void* g, void* l) {
  __builtin_amdgcn_global_load_lds(
      (const __attribute__((address_space(1))) unsigned int*)g,
      (__attribute__((address_space(3))) unsigned int*)l, 16, 0, 0);
}

// ---------------- pack bodies: f32 -> hi/lo bf16, tiled [panel][kq][r][8] ----------------
// tiled element offset = panel*(128*K) + kq*1024 + r*8 + s   (panel = row/128, kq = k/8)

__device__ __forceinline__ void pack_a_body(const float* __restrict__ A,
                                            float* __restrict__ Aout,   // optional passthrough copy
                                            unsigned short* __restrict__ hi,
                                            unsigned short* __restrict__ lo,
                                            int K, int bx, int by) {
  __shared__ float tile[32][33];
  const int t = threadIdx.x;
  const int tx = t & 31, ty8 = t >> 5;
  const int k0 = bx * 32, r0 = by * 32;
  #pragma unroll
  for (int r = ty8; r < 32; r += 8) {
    float v = A[(size_t)(r0 + r) * K + k0 + tx];
    tile[r][tx] = v;
    if (Aout) Aout[(size_t)(r0 + r) * K + k0 + tx] = v;
  }
  __syncthreads();
  if (t < 128) {
    const int kql = t >> 5;
    const int rl = t & 31;
    unsigned short h8[8], l8[8];
    #pragma unroll
    for (int s = 0; s < 8; s++) split2(tile[rl][kql * 8 + s], h8[s], l8[s]);
    const size_t panel = (size_t)(r0 >> 7);
    const int rloc = (r0 & 127) + rl;
    const size_t off = panel * (size_t)(128 * K) + (size_t)(k0 / 8 + kql) * 1024 + (size_t)rloc * 8;
    *(uint4*)(hi + off) = *(const uint4*)h8;
    *(uint4*)(lo + off) = *(const uint4*)l8;
  }
}

__device__ __forceinline__ void pack_ln_a_body(const float* __restrict__ A,
                                               const float* __restrict__ mu,
                                               const float* __restrict__ rstd,
                                               const float* __restrict__ g,
                                               const float* __restrict__ beta,
                                               unsigned short* __restrict__ hi,
                                               unsigned short* __restrict__ lo,
                                               int K, int bx, int by) {
  __shared__ float tile[32][33];
  const int t = threadIdx.x;
  const int tx = t & 31, ty8 = t >> 5;
  const int k0 = bx * 32, r0 = by * 32;
  #pragma unroll
  for (int r = ty8; r < 32; r += 8)
    tile[r][tx] = A[(size_t)(r0 + r) * K + k0 + tx];
  __syncthreads();
  if (t < 128) {
    const int kql = t >> 5;
    const int rl = t & 31;
    const int row = r0 + rl;
    const float m = mu[row], rs = rstd[row];
    float4 g0 = *(const float4*)(g + k0 + kql * 8);
    float4 g1 = *(const float4*)(g + k0 + kql * 8 + 4);
    float4 b0 = *(const float4*)(beta + k0 + kql * 8);
    float4 b1 = *(const float4*)(beta + k0 + kql * 8 + 4);
    float gv[8] = {g0.x, g0.y, g0.z, g0.w, g1.x, g1.y, g1.z, g1.w};
    float bv[8] = {b0.x, b0.y, b0.z, b0.w, b1.x, b1.y, b1.z, b1.w};
    unsigned short h8[8], l8[8];
    #pragma unroll
    for (int s = 0; s < 8; s++) {
      float v = (tile[rl][kql * 8 + s] - m) * rs * gv[s] + bv[s];
      split2(v, h8[s], l8[s]);
    }
    const size_t panel = (size_t)(r0 >> 7);
    const int rloc = (r0 & 127) + rl;
    const size_t off = panel * (size_t)(128 * K) + (size_t)(k0 / 8 + kql) * 1024 + (size_t)rloc * 8;
    *(uint4*)(hi + off) = *(const uint4*)h8;
    *(uint4*)(lo + off) = *(const uint4*)l8;
  }
}

__device__ __forceinline__ void pack_bt_body(const float* __restrict__ W,
                                             unsigned short* __restrict__ hi,
                                             unsigned short* __restrict__ lo,
                                             int K, int N, int bx, int by) {
  __shared__ float tile[32][33];   // tile[k_local][n_local]
  const int t = threadIdx.x;
  const int tx = t & 31, ty8 = t >> 5;
  const int k0 = bx * 32, n0 = by * 32;
  #pragma unroll
  for (int r = ty8; r < 32; r += 8)
    tile[r][tx] = W[(size_t)(k0 + r) * N + n0 + tx];
  __syncthreads();
  if (t < 128) {
    const int kql = t >> 5;
    const int nl = t & 31;
    unsigned short h8[8], l8[8];
    #pragma unroll
    for (int s = 0; s < 8; s++) split2(tile[kql * 8 + s][nl], h8[s], l8[s]);
    const size_t panel = (size_t)(n0 >> 7);
    const int nloc = (n0 & 127) + nl;
    const size_t off = panel * (size_t)(128 * K) + (size_t)(k0 / 8 + kql) * 1024 + (size_t)nloc * 8;
    *(uint4*)(hi + off) = *(const uint4*)h8;
    *(uint4*)(lo + off) = *(const uint4*)l8;
  }
}

// head pack: seq (+passthrough to out) and both H x FF weights in one dispatch.
// grid (32, 320): y<128 -> pack_a(seq); y<224 -> W_sm; else W_em
__global__ __launch_bounds__(256) void pack_head_kernel(const float* __restrict__ seq,
                                                        float* __restrict__ seq_out,
                                                        unsigned short* __restrict__ sh,
                                                        unsigned short* __restrict__ sl,
                                                        const float* __restrict__ W1,
                                                        const float* __restrict__ W2,
                                                        unsigned short* __restrict__ w1h,
                                                        unsigned short* __restrict__ w1l,
                                                        unsigned short* __restrict__ w2h,
                                                        unsigned short* __restrict__ w2l) {
  const int y = blockIdx.y;
  if (y < 128)      pack_a_body(seq, seq_out, sh, sl, H, blockIdx.x, y);
  else if (y < 224) pack_bt_body(W1, w1h, w1l, H, FF, blockIdx.x, y - 128);
  else              pack_bt_body(W2, w2h, w2l, H, FF, blockIdx.x, y - 224);
}

// mid pack: LN-fused A pack (start branch) + W_s2e B pack in one dispatch.
// grid (96, 224): y<128 -> pack_ln_a; else pack_bt(W_s2e)
__global__ __launch_bounds__(256) void pack_mid_kernel(const float* __restrict__ bufS,
                                                       const float* __restrict__ muS,
                                                       const float* __restrict__ rstdS,
                                                       const float* __restrict__ g,
                                                       const float* __restrict__ beta,
                                                       unsigned short* __restrict__ ahi,
                                                       unsigned short* __restrict__ alo,
                                                       const float* __restrict__ Ws2e,
                                                       unsigned short* __restrict__ wbh,
                                                       unsigned short* __restrict__ wbl) {
  const int y = blockIdx.y;
  if (y < 128) pack_ln_a_body(bufS, muS, rstdS, g, beta, ahi, alo, FF, blockIdx.x, y);
  else         pack_bt_body(Ws2e, wbh, wbl, FF, FF, blockIdx.x, y - 128);
}

// ---------------- MFMA GEMM core (32x32x16, 3-product split, double-buffered LDS) ----------------

template <int EPI>
__device__ __forceinline__ void gemm_body(const char* cAh, const char* cAl,
                                          const char* cBh, const char* cBl,
                                          const float* __restrict__ bias,
                                          float* __restrict__ C,
                                          int bm, int bn, int N, int K,
                                          char* smem) {
  const int tid = threadIdx.x;
  const int lane = tid & 63;
  const int wid = __builtin_amdgcn_readfirstlane(tid >> 6);
  const int wm = wid >> 1, wn = wid & 1;
  const int lb = lane * 16;
  const int ldsq = wid * 2048;

  const int khalf = lane >> 5;
  const int r31 = lane & 31;
  const int abase = khalf * 2048 + (wm * 64 + r31) * 16;
  const int bbase = khalf * 2048 + (wn * 64 + r31) * 16;

  f32x16 acc[2][2];
  #pragma unroll
  for (int a = 0; a < 2; a++)
    #pragma unroll
    for (int b = 0; b < 2; b++)
      #pragma unroll
      for (int r = 0; r < 16; r++) acc[a][b][r] = 0.0f;

  auto stage = [&](int buf, int k0) {
    const size_t qb = (size_t)((k0 >> 3) + wid) * 2048 + lb;
    char* sbuf = smem + buf * 32768 + ldsq;
    gld16(cAh + qb,        sbuf +     0);
    gld16(cAh + qb + 1024, sbuf +     0 + 1024);
    gld16(cAl + qb,        sbuf +  8192);
    gld16(cAl + qb + 1024, sbuf +  8192 + 1024);
    gld16(cBh + qb,        sbuf + 16384);
    gld16(cBh + qb + 1024, sbuf + 16384 + 1024);
    gld16(cBl + qb,        sbuf + 24576);
    gld16(cBl + qb + 1024, sbuf + 24576 + 1024);
  };

  stage(0, 0);
  for (int k0 = 0; k0 < K; k0 += 32) {
    const int cur = (k0 >> 5) & 1;
    __syncthreads();
    if (k0 + 32 < K) stage(cur ^ 1, k0 + 32);
    const char* sm = smem + cur * 32768;

    bf16x8 ah[2][2], al[2][2], bh[2][2], bl[2][2];
    #pragma unroll
    for (int ks = 0; ks < 2; ks++) {
      #pragma unroll
      for (int mt = 0; mt < 2; mt++) {
        ah[ks][mt] = *(const bf16x8*)(sm +     0 + ks * 4096 + abase + mt * 512);
        al[ks][mt] = *(const bf16x8*)(sm +  8192 + ks * 4096 + abase + mt * 512);
      }
      #pragma unroll
      for (int nt = 0; nt < 2; nt++) {
        bh[ks][nt] = *(const bf16x8*)(sm + 16384 + ks * 4096 + bbase + nt * 512);
        bl[ks][nt] = *(const bf16x8*)(sm + 24576 + ks * 4096 + bbase + nt * 512);
      }
    }
    #pragma unroll
    for (int ks = 0; ks < 2; ks++)
      #pragma unroll
      for (int mt = 0; mt < 2; mt++)
        #pragma unroll
        for (int nt = 0; nt < 2; nt++) {
          acc[mt][nt] = __builtin_amdgcn_mfma_f32_32x32x16_bf16(ah[ks][mt], bh[ks][nt], acc[mt][nt], 0, 0, 0);
          acc[mt][nt] = __builtin_amdgcn_mfma_f32_32x32x16_bf16(al[ks][mt], bh[ks][nt], acc[mt][nt], 0, 0, 0);
          acc[mt][nt] = __builtin_amdgcn_mfma_f32_32x32x16_bf16(ah[ks][mt], bl[ks][nt], acc[mt][nt], 0, 0, 0);
        }
  }

  #pragma unroll
  for (int mt = 0; mt < 2; mt++) {
    #pragma unroll
    for (int nt = 0; nt < 2; nt++) {
      const int colg = bn + wn * 64 + nt * 32 + r31;
      const float bb = bias[colg];
      #pragma unroll
      for (int reg = 0; reg < 16; reg++) {
        const int rowl = (reg & 3) + 8 * (reg >> 2) + 4 * khalf;
        const int rowg = bm + wm * 64 + mt * 32 + rowl;
        float v = acc[mt][nt][reg] + bb;
        if (EPI == 1) v = 0.5f * v * (1.0f + erff(v * 0.70710678118654752f));
        C[(size_t)rowg * N + colg] = v;
      }
    }
  }
}

// GEMM3: single output
__global__ __launch_bounds__(256) void gemm_mfma_kernel(const unsigned short* __restrict__ Ahi,
                                                        const unsigned short* __restrict__ Alo,
                                                        const unsigned short* __restrict__ Bhi,
                                                        const unsigned short* __restrict__ Blo,
                                                        const float* __restrict__ bias,
                                                        float* __restrict__ C,
                                                        int N, int K) {
  __shared__ __align__(16) char smem[65536];
  const size_t panAb = (size_t)blockIdx.y * (size_t)(128 * K) * 2;
  const size_t panBb = (size_t)blockIdx.x * (size_t)(128 * K) * 2;
  gemm_body<0>((const char*)Ahi + panAb, (const char*)Alo + panAb,
               (const char*)Bhi + panBb, (const char*)Blo + panBb,
               bias, C, blockIdx.y * 128, blockIdx.x * 128, N, K, smem);
}

// GEMM1+2 fused: blockIdx.z picks branch (same A), gelu epilogue
__global__ __launch_bounds__(256) void gemm_mfma_dual_kernel(const unsigned short* __restrict__ Ahi,
                                                             const unsigned short* __restrict__ Alo,
                                                             const unsigned short* __restrict__ B1hi,
                                                             const unsigned short* __restrict__ B1lo,
                                                             const unsigned short* __restrict__ B2hi,
                                                             const unsigned short* __restrict__ B2lo,
                                                             const float* __restrict__ bias1,
                                                             const float* __restrict__ bias2,
                                                             float* __restrict__ C1,
                                                             float* __restrict__ C2,
                                                             int N, int K) {
  __shared__ __align__(16) char smem[65536];
  const int zb = blockIdx.z;
  const unsigned short* Bhi = zb ? B2hi : B1hi;
  const unsigned short* Blo = zb ? B2lo : B1lo;
  const float* bias = zb ? bias2 : bias1;
  float* C = zb ? C2 : C1;
  const size_t panAb = (size_t)blockIdx.y * (size_t)(128 * K) * 2;
  const size_t panBb = (size_t)blockIdx.x * (size_t)(128 * K) * 2;
  gemm_body<1>((const char*)Ahi + panAb, (const char*)Alo + panAb,
               (const char*)Bhi + panBb, (const char*)Blo + panBb,
               bias, C, blockIdx.y * 128, blockIdx.x * 128, N, K, smem);
}

// ---------------- LN stats + logit (no writeback), both branches ----------------
// grid (S, 2): y=0 start branch, y=1 end branch

__global__ __launch_bounds__(256) void ln_stats_kernel(const float* __restrict__ HbS,
                                                       const float* __restrict__ HbE,
                                                       const float* __restrict__ gS,
                                                       const float* __restrict__ betaS,
                                                       const float* __restrict__ wS,
                                                       const float* __restrict__ bS,
                                                       const float* __restrict__ gE,
                                                       const float* __restrict__ betaE,
                                                       const float* __restrict__ wE,
                                                       const float* __restrict__ bE,
                                                       float* __restrict__ slog,
                                                       float* __restrict__ elog,
                                                       float* __restrict__ muS,
                                                       float* __restrict__ rstdS,
                                                       float* __restrict__ muE,
                                                       float* __restrict__ rstdE) {
  __shared__ float red[4];
  const int row = blockIdx.x, tid = threadIdx.x;
  const int br = blockIdx.y;
  const float* Hb = br ? HbE : HbS;
  const float* g = br ? gE : gS;
  const float* beta = br ? betaE : betaS;
  const float* w = br ? wE : wS;
  const float* bsc = br ? bE : bS;
  const float* h = Hb + (size_t)row * FF;

  float4 v[3];
  float s = 0.0f;
  #pragma unroll
  for (int t = 0; t < 3; t++) {
    v[t] = *(const float4*)(h + tid * 4 + t * 1024);
    s += v[t].x + v[t].y + v[t].z + v[t].w;
  }
  float mu = block_reduce_256(s, red) * (1.0f / (float)FF);

  float s2 = 0.0f;
  #pragma unroll
  for (int t = 0; t < 3; t++) {
    float dx = v[t].x - mu, dy = v[t].y - mu, dz = v[t].z - mu, dw = v[t].w - mu;
    s2 += dx * dx + dy * dy + dz * dz + dw * dw;
  }
  float var = block_reduce_256(s2, red) * (1.0f / (float)FF);
  float rstd = rsqrtf(var + 1e-5f);

  float dot = 0.0f;
  #pragma unroll
  for (int t = 0; t < 3; t++) {
    int idx = tid * 4 + t * 1024;
    float4 gv = *(const float4*)(g + idx);
    float4 bv = *(const float4*)(beta + idx);
    float4 wv = *(const float4*)(w + idx);
    float rx = (v[t].x - mu) * rstd * gv.x + bv.x;
    float ry = (v[t].y - mu) * rstd * gv.y + bv.y;
    float rz = (v[t].z - mu) * rstd * gv.z + bv.z;
    float rw = (v[t].w - mu) * rstd * gv.w + bv.w;
    dot += rx * wv.x + ry * wv.y + rz * wv.z + rw * wv.w;
  }
  float dt = block_reduce_256(dot, red);
  if (tid == 0) {
    if (br) { elog[row] = dt + bsc[0]; muE[row] = mu; rstdE[row] = rstd; }
    else    { slog[row] = dt + bsc[0]; muS[row] = mu; rstdS[row] = rstd; }
  }
}

// ---------------- band joint (inline E-LayerNorm, fused junk sum + 16-bit key histogram) ----------------

__global__ __launch_bounds__(256) void band_joint_kernel(const float* __restrict__ T,
                                                         const float* __restrict__ Eraw,
                                                         const float* __restrict__ muE,
                                                         const float* __restrict__ rstdE,
                                                         const float* __restrict__ gE,
                                                         const float* __restrict__ betaE,
                                                         const float* __restrict__ sl,
                                                         const float* __restrict__ el,
                                                         float* __restrict__ band,
                                                         double* __restrict__ jacc,
                                                         unsigned* __restrict__ hist16) {
  __shared__ float Elds[45][260];   // 260 = 256 + 4 pad
  __shared__ float red[4];
  const int t = threadIdx.x;
  const int bx = blockIdx.x;
  const int sbx = (bx & 7) * 32 + (bx >> 3);   // XCD-locality swizzle (perf heuristic)
  const int i0 = sbx * 16;
  const int r_l = t >> 4, c = t & 15;

  float accd[MAXSPAN];
  #pragma unroll
  for (int d = 0; d < MAXSPAN; d++) accd[d] = 0.0f;

  for (int k0 = 0; k0 < FF; k0 += 256) {
    const float* trow = T + (size_t)(i0 + r_l) * FF + k0 + c * 16;
    float4 tv0 = *(const float4*)(trow + 0);
    float4 tv1 = *(const float4*)(trow + 4);
    float4 tv2 = *(const float4*)(trow + 8);
    float4 tv3 = *(const float4*)(trow + 12);
    __syncthreads();
    for (int rr = t >> 6; rr < 45; rr += 4) {
      int gr = i0 + rr;
      int cc = (t & 63) * 4;
      float4 rv = {0.f, 0.f, 0.f, 0.f};
      if (gr < S) {
        float4 ev = *(const float4*)(Eraw + (size_t)gr * FF + k0 + cc);
        float m = muE[gr], rs = rstdE[gr];
        float4 gv = *(const float4*)(gE + k0 + cc);
        float4 bv = *(const float4*)(betaE + k0 + cc);
        rv.x = (ev.x - m) * rs * gv.x + bv.x;
        rv.y = (ev.y - m) * rs * gv.y + bv.y;
        rv.z = (ev.z - m) * rs * gv.z + bv.z;
        rv.w = (ev.w - m) * rs * gv.w + bv.w;
      }
      *(float4*)&Elds[rr][cc] = rv;
    }
    __syncthreads();
    #pragma unroll
    for (int d = 0; d < MAXSPAN; d++) {
      const float* er = &Elds[r_l + d][c * 16];
      float4 e0 = *(const float4*)(er + 0);
      float4 e1 = *(const float4*)(er + 4);
      float4 e2 = *(const float4*)(er + 8);
      float4 e3 = *(const float4*)(er + 12);
      accd[d] += tv0.x * e0.x + tv0.y * e0.y + tv0.z * e0.z + tv0.w * e0.w
               + tv1.x * e1.x + tv1.y * e1.y + tv1.z * e1.z + tv1.w * e1.w
               + tv2.x * e2.x + tv2.y * e2.y + tv2.z * e2.z + tv2.w * e2.w
               + tv3.x * e3.x + tv3.y * e3.y + tv3.z * e3.z + tv3.w * e3.w;
    }
  }

  const int i = i0 + r_l;
  const float my_sl = sl[i];
  float jsum = 0.0f;
  #pragma unroll
  for (int d = 0; d < MAXSPAN; d++) {
    float v = accd[d];
    v += __shfl_down(v, 8, 16);
    v += __shfl_down(v, 4, 16);
    v += __shfl_down(v, 2, 16);
    v += __shfl_down(v, 1, 16);
    if (c == 0) {
      int j = i + d;
      if (j < S) {
        float vv = v + my_sl + el[j];
        vv = fminf(fmaxf(vv, -10000.0f), 10000.0f);
        band[i * MAXSPAN + d] = vv;
        atomicAdd(&hist16[f2key(vv) >> 16], 1u);
        float p = 1.0f / (1.0f + expf(-vv));
        jsum += fmaxf(logf(1.0f - p), -100.0f);
      } else {
        band[i * MAXSPAN + d] = -1e30f;
      }
    }
  }
  float tot = block_reduce_256(jsum, red);
  if (t == 0) atomicAdd(jacc, (double)tot);
}

// ---------------- top-k + cost finalize (single block; threshold from precomputed hist) ----------------

__global__ __launch_bounds__(1024) void topk_finalize_kernel(const float* __restrict__ band,
                                                             const int* __restrict__ gold,
                                                             const double* __restrict__ jacc,
                                                             const unsigned* __restrict__ hist16,
                                                             float* __restrict__ out) {
  __shared__ int csum[1024];
  __shared__ unsigned sh_T16;
  __shared__ int sh_remk;
  __shared__ int sh_chunk, sh_above;
  __shared__ int idxbuf[1024];
  __shared__ unsigned tkey[256];
  __shared__ int tidx[256];
  __shared__ int cnt_gt, cnt_eq;
  __shared__ int sb[1024];
  __shared__ int gcell[G];
  __shared__ float redf[16];
  const int tid = threadIdx.x;

  // ---- threshold from 65536-bin histogram ----
  int s = 0;
  #pragma unroll 8
  for (int q = 0; q < 64; q++) s += (int)hist16[tid * 64 + q];
  csum[tid] = s;
  __syncthreads();
  // suffix sum (Hillis-Steele): csum[t] = sum over chunks >= t
  for (int off = 1; off < 1024; off <<= 1) {
    int v = (tid + off < 1024) ? csum[tid + off] : 0;
    __syncthreads();
    csum[tid] += v;
    __syncthreads();
  }
  // csum non-increasing; find chunk containing the rank-MAXK crossing
  {
    int nxt = (tid < 1023) ? csum[tid + 1] : 0;
    if (csum[tid] >= MAXK && nxt < MAXK) { sh_chunk = tid; sh_above = nxt; }
  }
  __syncthreads();
  if (tid == 0) {
    int cum = sh_above;            // count strictly above chunk's top bin range
    int b = sh_chunk * 64 + 63;
    for (;; b--) {
      int h = (int)hist16[b];
      if (cum + h >= MAXK || b == sh_chunk * 64) { sh_T16 = (unsigned)b; sh_remk = MAXK - cum; break; }
      cum += h;
    }
  }
  __syncthreads();
  const unsigned T16 = sh_T16;
  int remk = sh_remk;

  // ---- collect ----
  if (tid == 0) { cnt_gt = 0; cnt_eq = 0; }
  __syncthreads();
  for (int e = tid; e < NBAND; e += 1024) {
    unsigned key = f2key(band[e]);
    unsigned k16 = key >> 16;
    if (k16 >= T16) {
      int i = e / MAXSPAN, d = e - i * MAXSPAN;
      int fi = i * S + i + d;
      if (k16 > T16) {
        int p = atomicAdd(&cnt_gt, 1);
        if (p < 1024) idxbuf[p] = fi;
      } else {
        int p = atomicAdd(&cnt_eq, 1);
        if (p < 256) { tkey[p] = key; tidx[p] = fi; }
      }
    }
  }
  __syncthreads();
  if (tid == 0) {
    int ngt = cnt_gt < 1024 ? cnt_gt : 1024;
    int ne = cnt_eq < 256 ? cnt_eq : 256;
    for (int a2 = 1; a2 < ne; a2++) {
      unsigned kv = tkey[a2]; int iv = tidx[a2];
      int b2 = a2 - 1;
      while (b2 >= 0 && (tkey[b2] < kv || (tkey[b2] == kv && tidx[b2] > iv))) {
        tkey[b2 + 1] = tkey[b2]; tidx[b2 + 1] = tidx[b2]; b2--;
      }
      tkey[b2 + 1] = kv; tidx[b2 + 1] = iv;
    }
    int take = remk < ne ? remk : ne;
    for (int q = 0; q < take; q++)
      if (ngt + q < 1024) idxbuf[ngt + q] = tidx[q];
  }
  __syncthreads();

  // ---- bitonic sort of the MAXK indices (ascending) ----
  sb[tid] = (tid < MAXK) ? idxbuf[tid] : 0x7FFFFFFF;
  __syncthreads();
  for (int ksz = 2; ksz <= 1024; ksz <<= 1) {
    for (int jj = ksz >> 1; jj > 0; jj >>= 1) {
      int ixj = tid ^ jj;
      if (ixj > tid) {
        int a2 = sb[tid], b2 = sb[ixj];
        bool up = ((tid & ksz) == 0);
        if (up ? (a2 > b2) : (a2 < b2)) { sb[tid] = b2; sb[ixj] = a2; }
      }
      __syncthreads();
    }
  }
  if (tid < MAXK) {
    int fi = sb[tid];
    out[O_START + tid] = (float)(fi >> 12);
    out[O_END + tid]   = (float)(fi & 4095);
    out[O_MASK + tid]  = 1.0f;
  }

  // ---- cost finalize ----
  if (tid < G) {
    int gs = gold[2 * tid], ge = gold[2 * tid + 1];
    gcell[tid] = gs * MAXSPAN + (ge - gs);
  }
  __syncthreads();
  float tg = 0.0f, tj = 0.0f;
  if (tid < G) {
    int cell = gcell[tid];
    float x = band[cell];
    float p = 1.0f / (1.0f + expf(-x));
    tg = fmaxf(logf(p), -100.0f);
    bool first = true;
    for (int q = 0; q < tid; q++)
      if (gcell[q] == cell) { first = false; break; }
    if (first) tj = fmaxf(logf(1.0f - p), -100.0f);
  }
  float sg = block_reduce_1024(tg, redf);
  float sj = block_reduce_1024(tj, redf);
  if (tid == 0) {
    double junk = *jacc - (double)sj;   // exclude gold cells (set to 0 in reference)
    double cost = -((double)sg / (double)G) - (junk / BAND_COUNT);
    out[O_COST] = (float)cost;
  }
}

// ---------------- launch ----------------

extern "C" void kernel_launch(void* const* d_in, const int* in_sizes, int n_in,
                              void* d_out, int out_size, void* d_ws, size_t ws_size,
                              hipStream_t stream) {
  (void)in_sizes; (void)n_in; (void)out_size; (void)ws_size;
  const float* seq    = (const float*)d_in[0];
  const int*   gold   = (const int*)d_in[2];
  const float* W_sm   = (const float*)d_in[3];
  const float* b_sm   = (const float*)d_in[4];
  const float* g_sm   = (const float*)d_in[5];
  const float* be_sm  = (const float*)d_in[6];
  const float* W_em   = (const float*)d_in[7];
  const float* b_em   = (const float*)d_in[8];
  const float* g_em   = (const float*)d_in[9];
  const float* be_em  = (const float*)d_in[10];
  const float* w_st   = (const float*)d_in[11];
  const float* b_st   = (const float*)d_in[12];
  const float* w_en   = (const float*)d_in[13];
  const float* b_en   = (const float*)d_in[14];
  const float* W_s2e  = (const float*)d_in[15];
  const float* b_s2e  = (const float*)d_in[16];
  float* out = (float*)d_out;
  char* ws = (char*)d_ws;

  const size_t SZ_REP = (size_t)S * FF * 4;          // 50331648
  float*  bufS = (float*)(ws);                       // h_start f32 (gelu out, pre-LN)
  float*  bufE = (float*)(ws + SZ_REP);              // h_end f32 (gelu out, pre-LN)
  float*  bufT = (float*)(ws + 2 * SZ_REP);          // temp f32
  // R3: seq hi/lo tiled during GEMM1/2; reused as a3 (normalized start) hi/lo tiled
  char* R3 = ws + 3 * SZ_REP;
  unsigned short* seqhi = (unsigned short*)R3;
  unsigned short* seqlo = (unsigned short*)(R3 + (size_t)S * H * 2);
  unsigned short* a3hi  = (unsigned short*)R3;
  unsigned short* a3lo  = (unsigned short*)(R3 + (size_t)S * FF * 2);
  // R4: tiled weights. Phase 1: wb1/wb2 (H x FF). Phase 2: wb (FF x FF).
  char* R4 = ws + 4 * SZ_REP;
  const size_t SZ_W12 = (size_t)H * FF * 2;          // 6291456
  unsigned short* wb1hi = (unsigned short*)R4;
  unsigned short* wb1lo = (unsigned short*)(R4 + SZ_W12);
  unsigned short* wb2hi = (unsigned short*)(R4 + 2 * SZ_W12);
  unsigned short* wb2lo = (unsigned short*)(R4 + 3 * SZ_W12);
  unsigned short* wbhi = (unsigned short*)R4;
  unsigned short* wblo = (unsigned short*)(R4 + (size_t)FF * FF * 2);
  // R5: small buffers
  char* R5 = R4 + 2 * (size_t)FF * FF * 2;
  float*    band   = (float*)R5;                              // NBAND f32
  unsigned* hist16 = (unsigned*)(R5 + (size_t)NBAND * 4);     // 65536 bins
  double*   jacc   = (double*)(R5 + (size_t)NBAND * 4 + 262144);
  float*    slog   = (float*)(R5 + (size_t)NBAND * 4 + 262144 + 64);
  float*  elog  = slog + S;
  float*  muS   = elog + S;
  float*  rstdS = muS + S;
  float*  muE   = rstdS + S;
  float*  rstdE = muE + S;

  // zero hist16 + jacc in one memset (jacc sits right after hist16)
  hipMemsetAsync(hist16, 0, 262144 + 64 + 8, stream);

  dim3 gg(FF / 128, S / 128);        // (24, 32)
  dim3 gg2(FF / 128, S / 128, 2);    // fused GEMM1+2

  // head pack: seq (tiled hi/lo + passthrough copy to out) + both H x FF weights
  pack_head_kernel<<<dim3(32, 320), 256, 0, stream>>>(seq, out + O_SEQ, seqhi, seqlo,
                                                      W_sm, W_em, wb1hi, wb1lo, wb2hi, wb2lo);
  // fused GEMM1+2 (gelu epilogue, dbuf)
  gemm_mfma_dual_kernel<<<gg2, 256, 0, stream>>>(seqhi, seqlo, wb1hi, wb1lo, wb2hi, wb2lo,
                                                 b_sm, b_em, bufS, bufE, FF, H);
  // LN stats + logits for both branches, no writeback
  ln_stats_kernel<<<dim3(S, 2), 256, 0, stream>>>(bufS, bufE, g_sm, be_sm, w_st, b_st,
                                                  g_em, be_em, w_en, b_en,
                                                  slog, elog, muS, rstdS, muE, rstdE);
  // mid pack: LN-fused start pack + W_s2e pack in one dispatch
  pack_mid_kernel<<<dim3(96, 224), 256, 0, stream>>>(bufS, muS, rstdS, g_sm, be_sm,
                                                     a3hi, a3lo, W_s2e, wbhi, wblo);
  // GEMM3 (dbuf)
  gemm_mfma_kernel<<<gg, 256, 0, stream>>>(a3hi, a3lo, wbhi, wblo, b_s2e, bufT, FF, FF);

  // band joint with inline E-LayerNorm + fused junk-cost + 16-bit key histogram
  band_joint_kernel<<<S / 16, 256, 0, stream>>>(bufT, bufE, muE, rstdE, g_em, be_em,
                                                slog, elog, band, jacc, hist16);

  // top-k (threshold from hist) + cost finalize
  topk_finalize_kernel<<<1, 1024, 0, stream>>>(band, gold, jacc, hist16, out);
}